// Round 11
// baseline (7941.011 us; speedup 1.0000x reference)
//
#include <hip/hip_runtime.h>
#include <math.h>

typedef unsigned short u16;
typedef unsigned int u32;
typedef __attribute__((ext_vector_type(8))) short bf16x8;   // 8 bf16 lanes = 4 VGPR
typedef __attribute__((ext_vector_type(4))) float f32x4;

#define B_N 32
#define S_N 512
#define H_N 1024
#define HH_N 512
#define FRAME (B_N*H_N)        /* 32768 elems */
#define GBLK 32
#define EPS_F 1e-6f

#define MFMA16(a,b,c) __builtin_amdgcn_mfma_f32_16x16x32_bf16((a),(b),(c),0,0,0)
#define ATOM_ST(p,v) __hip_atomic_store((p),(v),__ATOMIC_RELAXED,__HIP_MEMORY_SCOPE_AGENT)

static __device__ __forceinline__ u16 f2bu(float v){      // fp32 -> bf16 bits (RNE)
  union{float f; unsigned u;} x; x.f = v;
  unsigned r = x.u + 0x7FFFu + ((x.u>>16)&1u);
  return (u16)(r>>16);
}
static __device__ __forceinline__ float bu2f(u16 s){
  union{unsigned u; float f;} x; x.u = ((unsigned)s)<<16; return x.f;
}
static __device__ __forceinline__ bf16x8 ld8(const u16* p){
  return *reinterpret_cast<const bf16x8*>(p);
}
static __device__ __forceinline__ void cvt8(const float* p, bf16x8& hi, bf16x8& lo){
  #pragma unroll
  for(int j=0;j<8;j++){
    float v = p[j];
    u16 h = f2bu(v);
    hi[j] = (short)h;
    lo[j] = (short)f2bu(v - bu2f(h));
  }
}

// ---------- fp32 1024x1024 transpose+convert: dst[c][k] = bf16(src[k][c]) ----
__global__ __launch_bounds__(256) void k_trcvt(const float* __restrict__ src,
    u16* __restrict__ dh, u16* __restrict__ dl){
  __shared__ float tile[32][33];
  int c0 = blockIdx.x*32, k0 = blockIdx.y*32;
  int tx = threadIdx.x & 31, ty = threadIdx.x >> 5;
  for(int i=ty;i<32;i+=8) tile[i][tx] = src[(size_t)(k0+i)*H_N + c0 + tx];
  __syncthreads();
  for(int i=ty;i<32;i+=8){
    float v = tile[tx][i];
    u16 h = f2bu(v);
    dh[(size_t)(c0+i)*H_N + k0 + tx] = h;
    if(dl) dl[(size_t)(c0+i)*H_N + k0 + tx] = f2bu(v - bu2f(h));
  }
}

// ---------- W_s padded fragment pack (hi only) --------------------------------
__global__ __launch_bounds__(256) void k_wspack(const float* __restrict__ Ws,
                                                u16* __restrict__ wsp){
  int gid = blockIdx.x*256 + threadIdx.x;        // 0..16383
  int j = gid & 7, l = (gid>>3) & 63, ks = gid >> 9;
  int lr = l & 15, lg = l >> 4;
  int k = ks*32 + lg*8 + j;
  wsp[gid] = (lr < 3) ? f2bu(Ws[k*3 + lr]) : (u16)0;
}

// ---------- precompute: xp = tanh(x@W_x+b_x), xr = x@W_r[:D] -----------------
__global__ __launch_bounds__(256) void k_pre(const float* __restrict__ x,
    const u16* __restrict__ WxTh, const u16* __restrict__ WxTl,
    const u16* __restrict__ WrxTh, const u16* __restrict__ WrxTl,
    const float* __restrict__ b_x,
    u16* __restrict__ xp, u16* __restrict__ xplo,
    u16* __restrict__ xr, u16* __restrict__ xrlo){
  int tid = threadIdx.x, l = tid&63, wid = tid>>6;
  int wm = wid>>1, wn = wid&1, lr = l&15, lg = l>>4;
  int mbase = blockIdx.y*64 + wm*32;
  int nblk = blockIdx.x*64;
  bool isX = (nblk < H_N);
  int nbase = nblk + wn*32;
  const u16* WTh = isX? WxTh : WrxTh;
  const u16* WTl = isX? WxTl : WrxTl;
  int nw0 = isX? nbase : (nbase - H_N);
  const float* ar[2]; const u16* brh[2]; const u16* brl[2];
  #pragma unroll
  for(int mt=0;mt<2;mt++){
    int m = mbase + mt*16 + lr;
    ar[mt] = x + ((size_t)(m & (B_N-1))*S_N + (m>>5))*H_N;   // m = t*32 + b
  }
  #pragma unroll
  for(int nt=0;nt<2;nt++){
    brh[nt] = WTh + (size_t)(nw0 + nt*16 + lr)*H_N;
    brl[nt] = WTl + (size_t)(nw0 + nt*16 + lr)*H_N;
  }
  f32x4 zz = {0.f,0.f,0.f,0.f};
  f32x4 acc[2][2] = {{zz,zz},{zz,zz}};
  for(int ks=0;ks<32;ks++){
    int ke = ks*32 + lg*8;
    bf16x8 ah[2], al[2], bh[2], bl[2];
    #pragma unroll
    for(int mt=0;mt<2;mt++) cvt8(ar[mt]+ke, ah[mt], al[mt]);
    #pragma unroll
    for(int nt=0;nt<2;nt++){ bh[nt] = ld8(brh[nt]+ke); bl[nt] = ld8(brl[nt]+ke); }
    #pragma unroll
    for(int mt=0;mt<2;mt++)
      #pragma unroll
      for(int nt=0;nt<2;nt++){
        acc[mt][nt] = MFMA16(ah[mt],bh[nt],acc[mt][nt]);
        acc[mt][nt] = MFMA16(al[mt],bh[nt],acc[mt][nt]);
        acc[mt][nt] = MFMA16(ah[mt],bl[nt],acc[mt][nt]);
      }
  }
  #pragma unroll
  for(int mt=0;mt<2;mt++)
    #pragma unroll
    for(int nt=0;nt<2;nt++){
      int n = nbase + nt*16 + lr;
      #pragma unroll
      for(int i=0;i<4;i++){
        int m = mbase + mt*16 + lg*4 + i;
        size_t idx = (size_t)m*H_N + (isX? n : (n - H_N));
        float v = acc[mt][nt][i];
        if(isX){
          float tv = tanhf(v + b_x[n]);
          u16 h = f2bu(tv);
          xp[idx] = h;
          if(xplo) xplo[idx] = f2bu(tv - bu2f(h));
        }else{
          u16 h = f2bu(v);
          xr[idx] = h;
          if(xrlo) xrlo[idx] = f2bu(v - bu2f(h));
        }
      }
    }
}

// ---------- final: out[b][t][:] = tanh(h(t,b,:) @ W_o + b_o) (fp32) ----------
// hall is BLOCK-MAJOR: hall[t][owner][row][c], c in [0,32):
//   c<16 -> global col owner*16+c ; c>=16 -> owner*16 + 512 + (c-16)
__global__ __launch_bounds__(256) void k_fin(const u16* __restrict__ hall,
    const u16* __restrict__ WoTh, const u16* __restrict__ WoTl,
    const float* __restrict__ b_o, float* __restrict__ out){
  int tid = threadIdx.x, l = tid&63, wid = tid>>6;
  int wm = wid>>1, wn = wid&1, lr = l&15, lg = l>>4;
  int mbase = blockIdx.y*64 + wm*32;
  int nbase = blockIdx.x*64 + wn*32;
  size_t arowB[2]; const u16* brh[2]; const u16* brl[2];
  #pragma unroll
  for(int mt=0;mt<2;mt++){
    int m = mbase + mt*16 + lr;                       // m = t*32 + b
    arowB[mt] = (size_t)(m>>5)*FRAME + (size_t)(m&31)*32;
  }
  #pragma unroll
  for(int nt=0;nt<2;nt++){
    brh[nt] = WoTh + (size_t)(nbase + nt*16 + lr)*H_N;
    brl[nt] = WoTl + (size_t)(nbase + nt*16 + lr)*H_N;
  }
  int lgadd = (lg>>1)*1024 + (lg&1)*8;
  f32x4 zz = {0.f,0.f,0.f,0.f};
  f32x4 acc[2][2] = {{zz,zz},{zz,zz}};
  for(int ks=0;ks<32;ks++){
    int ke = ks*32 + lg*8;
    int abase = (2*(ks&15))*1024 + lgadd + ((ks>=16)?16:0);
    #pragma unroll
    for(int mt=0;mt<2;mt++){
      bf16x8 a = ld8(hall + arowB[mt] + abase);
      #pragma unroll
      for(int nt=0;nt<2;nt++){
        acc[mt][nt] = MFMA16(a, ld8(brh[nt]+ke), acc[mt][nt]);
        acc[mt][nt] = MFMA16(a, ld8(brl[nt]+ke), acc[mt][nt]);
      }
    }
  }
  #pragma unroll
  for(int mt=0;mt<2;mt++)
    #pragma unroll
    for(int nt=0;nt<2;nt++){
      int n = nbase + nt*16 + lr;
      float bo = b_o[n];
      #pragma unroll
      for(int i=0;i<4;i++){
        int m = mbase + mt*16 + lg*4 + i;
        int b = m & (B_N-1), t = m >> 5;
        out[((size_t)b*S_N + t)*H_N + n] = tanhf(acc[mt][nt][i] + bo);
      }
    }
}

// ---------- persistent recurrence: 32 blocks x 256 threads -------------------
// DATAFLOW step: each wave (K-quarter kq) depends on only 16 owner blocks
// (8 owner-pairs = 8 MFMA fragments). Poll those flags in parallel (ballot);
// consume each pair the moment it's ready -> h-load latency and MFMA overlap
// with waiting for laggards. Per-wave private LDS partials -> 3 syncs/step.
__global__ __launch_bounds__(256) void k_recur(
    const u16* __restrict__ xp, const u16* __restrict__ xplo0,
    const u16* __restrict__ xr, const u16* __restrict__ xrlo0, int xlostep,
    const u16* __restrict__ WhTh, const u16* __restrict__ WhTl,
    const u16* __restrict__ WrTh, const u16* __restrict__ wsp,
    const float* __restrict__ b_h, const float* __restrict__ b_r,
    const float* __restrict__ b_s,
    const float* __restrict__ mob_a, const float* __restrict__ mob_b,
    const float* __restrict__ mob_c, const float* __restrict__ mob_d,
    const u16* __restrict__ zhi, u16* __restrict__ lob,
    u16* __restrict__ hall, float* __restrict__ hf, int* __restrict__ arr)
{
  __shared__ float Cpart[4][2688];     // per-wave 32 rows x 84-stride (80 used)
  __shared__ float mobp[16*25];
  __shared__ float bias[64];
  __shared__ float bsv[3];
  __shared__ float hfL[32][33];        // fp32 master h, block-private
  int tid = threadIdx.x, bid = blockIdx.x;
  int P0 = bid*16;
  int l = tid&63, kq = tid>>6;
  int lr = l&15, lg = l>>4;

  // one-time staging of per-block params
  for(int idx=tid; idx<384; idx+=256){
    int j = idx/24, c = idx%24, cyc = c>>3, q = c&7;
    const float* arrp = (q<2)? mob_a : (q<4)? mob_b : (q<6)? mob_c : mob_d;
    mobp[j*25 + c] = arrp[cyc*H_N + (q&1)*HH_N + P0 + j];
  }
  if(tid < 64){
    int grp = tid>>4, jj = tid&15;
    bias[tid] = ((grp<2)? b_h : b_r)[P0 + jj + ((grp&1)? HH_N : 0)];
  } else if(tid < 67){
    bsv[tid-64] = b_s[tid-64];
  }
  for(int idx=tid; idx<32*33; idx+=256) (&hfL[0][0])[idx] = 0.f;

  const u16* bhOh = WhTh + (size_t)(P0 + lr)*H_N;
  const u16* bhOl = WhTl + (size_t)(P0 + lr)*H_N;
  const u16* bhPh = WhTh + (size_t)(P0 + HH_N + lr)*H_N;
  const u16* bhPl = WhTl + (size_t)(P0 + HH_N + lr)*H_N;
  const u16* brO  = WrTh + (size_t)(P0 + lr)*H_N;
  const u16* brP  = WrTh + (size_t)(P0 + HH_N + lr)*H_N;
  const u16* wps  = wsp + (size_t)(kq*8)*512 + l*8;
  // block-major A addressing
  int lgadd = (lg>>1)*1024 + (lg&1)*8 + ((kq>=2)?16:0);
  int row0t = lr*32, row1t = (16+lr)*32;
  int ob = (kq&1)*16;                           // this wave's owner base
  // elementwise mapping: thread = (row, pair-duo)
  int erow = tid>>3, ejj = (tid&7)*2;
  size_t ei0 = (size_t)erow*H_N + P0 + ejj;
  size_t ei1 = ei0 + HH_N;

  __syncthreads();

  for(int t=0; t<S_N; t++){
    const u16* hihB = (t==0)? zhi : (hall + (size_t)(t-1)*FRAME);
    const u16* hilB = lob + (size_t)(t&1)*FRAME;
    const u16* xp_t   = xp + (size_t)t*FRAME;
    const u16* xr_t   = xr + (size_t)t*FRAME;
    const u16* xplo_t = xplo0 + (size_t)t*xlostep;
    const u16* xrlo_t = xrlo0 + (size_t)t*xlostep;

    // prefetch elementwise inputs early (independent of h / flags)
    u32 pxpL = *(const u32*)(xp_t   + ei0);
    u32 pxpH = *(const u32*)(xp_t   + ei1);
    u32 ploL = *(const u32*)(xplo_t + ei0);
    u32 ploH = *(const u32*)(xplo_t + ei1);
    u32 pxrL = *(const u32*)(xr_t   + ei0);
    u32 pxrH = *(const u32*)(xr_t   + ei1);
    u32 prlL = *(const u32*)(xrlo_t + ei0);
    u32 prlH = *(const u32*)(xrlo_t + ei1);

    f32x4 zz = {0.f,0.f,0.f,0.f};
    f32x4 cO0=zz,cO1=zz,cP0=zz,cP1=zz,rOa=zz,rOb=zz,rPa=zz,rPb=zz,sA=zz,sB=zz;

    // ---- dataflow consume: 8 owner-pairs, processed on arrival ----
    unsigned rem = 0xFFu;
    while(rem){
      int f = 0x7fffffff;
      if(l < 16)
        f = __hip_atomic_load(&arr[(ob + l)<<5], __ATOMIC_ACQUIRE, __HIP_MEMORY_SCOPE_AGENT);
      unsigned long long bal = __ballot(f >= t);
      unsigned own = (unsigned)bal & 0xFFFFu;            // owner ob+j ready
      unsigned pr  = own & (own>>1) & 0x5555u;           // bit 2i: pair i ready
      while(pr){
        int b2 = __ffs(pr)-1; pr &= pr-1;
        int i = b2 >> 1;
        if(!(rem & (1u<<i))) continue;
        rem &= ~(1u<<i);
        int ke = (kq*8+i)*32 + lg*8;
        int abase = (2*((kq&1)*8+i))*1024 + lgadd;
        bf16x8 ah0 = ld8(hihB + abase + row0t);
        bf16x8 ah1 = ld8(hihB + abase + row1t);
        bf16x8 al0 = ld8(hilB + abase + row0t);
        bf16x8 al1 = ld8(hilB + abase + row1t);
        bf16x8 fOh = ld8(bhOh+ke), fOl = ld8(bhOl+ke);
        bf16x8 fPh = ld8(bhPh+ke), fPl = ld8(bhPl+ke);
        bf16x8 frO_ = ld8(brO+ke), frP_ = ld8(brP+ke);
        bf16x8 fs   = ld8(wps + i*512);
        cO0 = MFMA16(ah0,fOh,cO0); cO0 = MFMA16(al0,fOh,cO0); cO0 = MFMA16(ah0,fOl,cO0);
        cO1 = MFMA16(ah1,fOh,cO1); cO1 = MFMA16(al1,fOh,cO1); cO1 = MFMA16(ah1,fOl,cO1);
        cP0 = MFMA16(ah0,fPh,cP0); cP0 = MFMA16(al0,fPh,cP0); cP0 = MFMA16(ah0,fPl,cP0);
        cP1 = MFMA16(ah1,fPh,cP1); cP1 = MFMA16(al1,fPh,cP1); cP1 = MFMA16(ah1,fPl,cP1);
        rOa = MFMA16(ah0,frO_,rOa); rOa = MFMA16(al0,frO_,rOa);
        rOb = MFMA16(ah1,frO_,rOb); rOb = MFMA16(al1,frO_,rOb);
        rPa = MFMA16(ah0,frP_,rPa); rPa = MFMA16(al0,frP_,rPa);
        rPb = MFMA16(ah1,frP_,rPb); rPb = MFMA16(al1,frP_,rPb);
        sA  = MFMA16(ah0,fs, sA);  sA  = MFMA16(al0,fs, sA);
        sB  = MFMA16(ah1,fs, sB);  sB  = MFMA16(al1,fs, sB);
      }
      if(rem) __builtin_amdgcn_s_sleep(1);
    }

    // ---- per-wave private partials (no inter-wave hazard) ----
    float* W = Cpart[kq];
    #pragma unroll
    for(int i=0;i<4;i++){
      int r0 = (lg*4+i)*84, r1 = (16+lg*4+i)*84;
      W[r0 +      lr] = cO0[i];  W[r1 +      lr] = cO1[i];
      W[r0 + 16 + lr] = cP0[i];  W[r1 + 16 + lr] = cP1[i];
      W[r0 + 32 + lr] = rOa[i];  W[r1 + 32 + lr] = rOb[i];
      W[r0 + 48 + lr] = rPa[i];  W[r1 + 48 + lr] = rPb[i];
      W[r0 + 64 + lr] = sA[i];   W[r1 + 64 + lr] = sB[i];
    }
    __syncthreads();
    // merge 4 regions -> Cpart[0]; div-free mapping, 10 cols per thread
    {
      int r = tid>>3, c0m = (tid&7)*10;
      #pragma unroll
      for(int cc=0;cc<10;cc++){
        int e = r*84 + c0m + cc;
        Cpart[0][e] = Cpart[0][e] + Cpart[1][e] + Cpart[2][e] + Cpart[3][e];
      }
    }
    __syncthreads();

    // ---- elementwise with fused per-row softmax-gate ----
    {
      const float* C0 = Cpart[0];
      float l0 = C0[erow*84+64] + bsv[0];
      float l1 = C0[erow*84+65] + bsv[1];
      float l2 = C0[erow*84+66] + bsv[2];
      float mx = fmaxf(l0, fmaxf(l1,l2));
      float e0 = expf(l0-mx), e1 = expf(l1-mx), e2 = expf(l2-mx);
      float sb = (e0 + 0.5f*e1 + 0.25f*e2) / (e0+e1+e2);
      u16 nob[2], npb[2], loO[2], loP[2];
      #pragma unroll
      for(int d=0; d<2; d++){
        int j = ejj + d;
        float xpv0 = bu2f((u16)(pxpL>>(16*d))) + bu2f((u16)(ploL>>(16*d)));
        float xpv1 = bu2f((u16)(pxpH>>(16*d))) + bu2f((u16)(ploH>>(16*d)));
        float xrv0 = bu2f((u16)(pxrL>>(16*d))) + bu2f((u16)(prlL>>(16*d)));
        float xrv1 = bu2f((u16)(pxrH>>(16*d))) + bu2f((u16)(prlH>>(16*d)));
        float zo = tanhf(xpv0 + C0[erow*84 + j]      + bias[j]);
        float zp = tanhf(xpv1 + C0[erow*84 + 16 + j] + bias[16+j]);
        float ro = 1.f/(1.f + expf(-(xrv0 + C0[erow*84 + 32 + j] + bias[32+j])));
        float rp = 1.f/(1.f + expf(-(xrv1 + C0[erow*84 + 48 + j] + bias[48+j])));
        const float* mp = &mobp[j*25];
        #pragma unroll
        for(int cy=0;cy<3;cy++){
          float are=mp[cy*8+0], aim=mp[cy*8+1], bre=mp[cy*8+2], bim=mp[cy*8+3];
          float cre=mp[cy*8+4], cim=mp[cy*8+5], dre=mp[cy*8+6], dim_=mp[cy*8+7];
          float nre = are*zo - aim*zp + bre;
          float nim = are*zp + aim*zo + bim;
          float de  = cre*zo - cim*zp + dre;
          float di  = cre*zp + cim*zo + dim_;
          float inv = 1.f/(de*de + di*di + EPS_F);
          float nzo = (nre*de + nim*di)*inv;
          float nzp = (nim*de - nre*di)*inv;
          zo = nzo; zp = nzp;
        }
        ro *= sb; rp *= sb;
        float ho = hfL[erow][j], hp2 = hfL[erow][16+j];
        float no  = (1.f-ro)*ho + ro*zo;
        float np2 = (1.f-rp)*hp2 + rp*zp;
        hfL[erow][j] = no; hfL[erow][16+j] = np2;
        nob[d] = f2bu(no);  npb[d] = f2bu(np2);
        loO[d] = f2bu(no  - bu2f(nob[d]));
        loP[d] = f2bu(np2 - bu2f(npb[d]));
      }
      size_t bb = (size_t)bid*1024 + (size_t)erow*32 + ejj;
      u16* hallT = hall + (size_t)t*FRAME;
      u16* lonT  = lob + (size_t)((t+1)&1)*FRAME;
      ATOM_ST((u32*)(hallT + bb),      (u32)nob[0] | ((u32)nob[1]<<16));
      ATOM_ST((u32*)(hallT + bb + 16), (u32)npb[0] | ((u32)npb[1]<<16));
      ATOM_ST((u32*)(lonT  + bb),      (u32)loO[0] | ((u32)loO[1]<<16));
      ATOM_ST((u32*)(lonT  + bb + 16), (u32)loP[0] | ((u32)loP[1]<<16));
    }

    // publish: drain stores (syncthreads waits vmcnt), release own flag
    __syncthreads();
    if(tid == 0)
      __hip_atomic_store(&arr[bid<<5], t+1, __ATOMIC_RELEASE, __HIP_MEMORY_SCOPE_AGENT);
  }

  // write fp32 master h out for k_tail
  for(int idx=tid; idx<1024; idx+=256){
    int r = idx>>5, c = idx&31;
    int g = (c<16)? (P0+c) : (P0 + HH_N + (c-16));
    hf[(size_t)r*H_N + g] = hfL[r][c];
  }
}

// ---------- tail: of/pf (fp32) from fp32 master h ----------------------------
__global__ __launch_bounds__(256) void k_tail(const float* __restrict__ hf,
                                              float* __restrict__ out){
  int i = blockIdx.x*256 + threadIdx.x;   // 0..32767
  int b = i >> 10, c = i & 1023;
  float v = hf[(size_t)b*H_N + c];
  size_t base = (size_t)B_N*S_N*H_N;
  size_t idx = (c < HH_N) ? base + (size_t)b*HH_N + c
                          : base + (size_t)B_N*HH_N + (size_t)b*HH_N + (c - HH_N);
  out[idx] = v;
}

// ---------- host -------------------------------------------------------------
extern "C" void kernel_launch(void* const* d_in, const int* in_sizes, int n_in,
                              void* d_out, int out_size, void* d_ws, size_t ws_size,
                              hipStream_t stream)
{
  const float* x    = (const float*)d_in[0];
  const float* W_x  = (const float*)d_in[1];
  const float* b_x  = (const float*)d_in[2];
  const float* W_h  = (const float*)d_in[3];
  const float* b_h  = (const float*)d_in[4];
  const float* W_r  = (const float*)d_in[5];
  const float* b_r  = (const float*)d_in[6];
  const float* W_s  = (const float*)d_in[7];
  const float* b_s  = (const float*)d_in[8];
  const float* mob_a= (const float*)d_in[9];
  const float* mob_b= (const float*)d_in[10];
  const float* mob_c= (const float*)d_in[11];
  const float* mob_d= (const float*)d_in[12];
  const float* W_o  = (const float*)d_in[13];
  const float* b_o  = (const float*)d_in[14];
  float* out = (float*)d_out;

  char* ws = (char*)d_ws;
  size_t off = 0;
  auto carve = [&](size_t bytes)->char*{
    char* p = ws + off; off = (off + bytes + 255) & ~(size_t)255; return p;
  };
  int*   arr  = (int*)carve(4096);                          // 32 flags, 128B apart
  float* hf   = (float*)carve((size_t)FRAME*sizeof(float));
  u16*   zhi  = (u16*)carve((size_t)FRAME*sizeof(u16));     // zero h / zero lo frame
  u16*   lob  = (u16*)carve((size_t)2*FRAME*sizeof(u16));
  size_t hdr_bytes = off;                                   // zeroed region
  u16*   WhTh = (u16*)carve((size_t)H_N*H_N*sizeof(u16));
  u16*   WhTl = (u16*)carve((size_t)H_N*H_N*sizeof(u16));
  u16*   WrTh = (u16*)carve((size_t)H_N*H_N*sizeof(u16));
  u16*   wsp  = (u16*)carve((size_t)32*512*sizeof(u16));
  u16*   hall = (u16*)carve((size_t)S_N*FRAME*sizeof(u16));
  u16*   xp   = (u16*)carve((size_t)S_N*FRAME*sizeof(u16));
  u16*   xr   = (u16*)carve((size_t)S_N*FRAME*sizeof(u16));
  size_t base_off = off;
  size_t lo_bytes = (size_t)S_N*FRAME*sizeof(u16);
  bool haslo = (ws_size >= base_off + 2*lo_bytes + 4096);
  u16* xplo = nullptr; u16* xrlo = nullptr;
  if(haslo){
    xplo = (u16*)carve(lo_bytes);
    xrlo = (u16*)carve(lo_bytes);
  }

  const size_t WSZ = (size_t)H_N*H_N;
  u16* WxTh  = hall;             // hall frames 0..127: dead after k_pre
  u16* WxTl  = hall + WSZ;
  u16* WrxTh = hall + 2*WSZ;
  u16* WrxTl = hall + 3*WSZ;
  u16* WoTh  = xp;               // xp dead after recurrence
  u16* WoTl  = xp + WSZ;

  (void)hipMemsetAsync(d_ws, 0, hdr_bytes, stream);

  k_trcvt<<<dim3(32,32),256,0,stream>>>(W_h, WhTh, WhTl);
  k_trcvt<<<dim3(32,32),256,0,stream>>>(W_r + (size_t)H_N*H_N, WrTh, (u16*)nullptr);
  k_trcvt<<<dim3(32,32),256,0,stream>>>(W_x, WxTh, WxTl);
  k_trcvt<<<dim3(32,32),256,0,stream>>>(W_r, WrxTh, WrxTl);
  k_wspack<<<64,256,0,stream>>>(W_s, wsp);
  k_pre<<<dim3(32,256),256,0,stream>>>(x, WxTh, WxTl, WrxTh, WrxTl, b_x,
                                       xp, xplo, xr, xrlo);

  k_recur<<<GBLK,256,0,stream>>>(
      xp, haslo ? xplo : zhi, xr, haslo ? xrlo : zhi, haslo ? FRAME : 0,
      WhTh, WhTl, WrTh, wsp, b_h, b_r, b_s,
      mob_a, mob_b, mob_c, mob_d, zhi, lob, hall, hf, arr);

  k_trcvt<<<dim3(32,32),256,0,stream>>>(W_o, WoTh, WoTl);   // into dead xp
  k_fin<<<dim3(16,256),256,0,stream>>>(hall, WoTh, WoTl, b_o, out);
  k_tail<<<128,256,0,stream>>>(hf, out);
}

// Round 12
// 6567.097 us; speedup vs baseline: 1.2092x; 1.2092x over previous
//
#include <hip/hip_runtime.h>
#include <math.h>

typedef unsigned short u16;
typedef unsigned int u32;
typedef __attribute__((ext_vector_type(8))) short bf16x8;   // 8 bf16 lanes = 4 VGPR
typedef __attribute__((ext_vector_type(4))) float f32x4;

#define B_N 32
#define S_N 512
#define H_N 1024
#define HH_N 512
#define FRAME (B_N*H_N)        /* 32768 elems */
#define GBLK 64
#define EPS_F 1e-6f

#define MFMA16(a,b,c) __builtin_amdgcn_mfma_f32_16x16x32_bf16((a),(b),(c),0,0,0)
#define ATOM_ST(p,v) __hip_atomic_store((p),(v),__ATOMIC_RELAXED,__HIP_MEMORY_SCOPE_AGENT)

static __device__ __forceinline__ u16 f2bu(float v){      // fp32 -> bf16 bits (RNE)
  union{float f; unsigned u;} x; x.f = v;
  unsigned r = x.u + 0x7FFFu + ((x.u>>16)&1u);
  return (u16)(r>>16);
}
static __device__ __forceinline__ float bu2f(u16 s){
  union{unsigned u; float f;} x; x.u = ((unsigned)s)<<16; return x.f;
}
static __device__ __forceinline__ bf16x8 ld8(const u16* p){
  return *reinterpret_cast<const bf16x8*>(p);
}
static __device__ __forceinline__ void cvt8(const float* p, bf16x8& hi, bf16x8& lo){
  #pragma unroll
  for(int j=0;j<8;j++){
    float v = p[j];
    u16 h = f2bu(v);
    hi[j] = (short)h;
    lo[j] = (short)f2bu(v - bu2f(h));
  }
}

// ---------- fp32 1024x1024 transpose+convert: dst[c][k] = bf16(src[k][c]) ----
__global__ __launch_bounds__(256) void k_trcvt(const float* __restrict__ src,
    u16* __restrict__ dh, u16* __restrict__ dl){
  __shared__ float tile[32][33];
  int c0 = blockIdx.x*32, k0 = blockIdx.y*32;
  int tx = threadIdx.x & 31, ty = threadIdx.x >> 5;
  for(int i=ty;i<32;i+=8) tile[i][tx] = src[(size_t)(k0+i)*H_N + c0 + tx];
  __syncthreads();
  for(int i=ty;i<32;i+=8){
    float v = tile[tx][i];
    u16 h = f2bu(v);
    dh[(size_t)(c0+i)*H_N + k0 + tx] = h;
    if(dl) dl[(size_t)(c0+i)*H_N + k0 + tx] = f2bu(v - bu2f(h));
  }
}

// ---------- W_s padded fragment pack (hi only) --------------------------------
__global__ __launch_bounds__(256) void k_wspack(const float* __restrict__ Ws,
                                                u16* __restrict__ wsp){
  int gid = blockIdx.x*256 + threadIdx.x;        // 0..16383
  int j = gid & 7, l = (gid>>3) & 63, ks = gid >> 9;
  int lr = l & 15, lg = l >> 4;
  int k = ks*32 + lg*8 + j;
  wsp[gid] = (lr < 3) ? f2bu(Ws[k*3 + lr]) : (u16)0;
}

// ---------- precompute: xp = tanh(x@W_x+b_x), xr = x@W_r[:D] -----------------
__global__ __launch_bounds__(256) void k_pre(const float* __restrict__ x,
    const u16* __restrict__ WxTh, const u16* __restrict__ WxTl,
    const u16* __restrict__ WrxTh, const u16* __restrict__ WrxTl,
    const float* __restrict__ b_x,
    u16* __restrict__ xp, u16* __restrict__ xplo,
    u16* __restrict__ xr, u16* __restrict__ xrlo){
  int tid = threadIdx.x, l = tid&63, wid = tid>>6;
  int wm = wid>>1, wn = wid&1, lr = l&15, lg = l>>4;
  int mbase = blockIdx.y*64 + wm*32;
  int nblk = blockIdx.x*64;
  bool isX = (nblk < H_N);
  int nbase = nblk + wn*32;
  const u16* WTh = isX? WxTh : WrxTh;
  const u16* WTl = isX? WxTl : WrxTl;
  int nw0 = isX? nbase : (nbase - H_N);
  const float* ar[2]; const u16* brh[2]; const u16* brl[2];
  #pragma unroll
  for(int mt=0;mt<2;mt++){
    int m = mbase + mt*16 + lr;
    ar[mt] = x + ((size_t)(m & (B_N-1))*S_N + (m>>5))*H_N;   // m = t*32 + b
  }
  #pragma unroll
  for(int nt=0;nt<2;nt++){
    brh[nt] = WTh + (size_t)(nw0 + nt*16 + lr)*H_N;
    brl[nt] = WTl + (size_t)(nw0 + nt*16 + lr)*H_N;
  }
  f32x4 zz = {0.f,0.f,0.f,0.f};
  f32x4 acc[2][2] = {{zz,zz},{zz,zz}};
  for(int ks=0;ks<32;ks++){
    int ke = ks*32 + lg*8;
    bf16x8 ah[2], al[2], bh[2], bl[2];
    #pragma unroll
    for(int mt=0;mt<2;mt++) cvt8(ar[mt]+ke, ah[mt], al[mt]);
    #pragma unroll
    for(int nt=0;nt<2;nt++){ bh[nt] = ld8(brh[nt]+ke); bl[nt] = ld8(brl[nt]+ke); }
    #pragma unroll
    for(int mt=0;mt<2;mt++)
      #pragma unroll
      for(int nt=0;nt<2;nt++){
        acc[mt][nt] = MFMA16(ah[mt],bh[nt],acc[mt][nt]);
        acc[mt][nt] = MFMA16(al[mt],bh[nt],acc[mt][nt]);
        acc[mt][nt] = MFMA16(ah[mt],bl[nt],acc[mt][nt]);
      }
  }
  #pragma unroll
  for(int mt=0;mt<2;mt++)
    #pragma unroll
    for(int nt=0;nt<2;nt++){
      int n = nbase + nt*16 + lr;
      #pragma unroll
      for(int i=0;i<4;i++){
        int m = mbase + mt*16 + lg*4 + i;
        size_t idx = (size_t)m*H_N + (isX? n : (n - H_N));
        float v = acc[mt][nt][i];
        if(isX){
          float tv = tanhf(v + b_x[n]);
          u16 h = f2bu(tv);
          xp[idx] = h;
          if(xplo) xplo[idx] = f2bu(tv - bu2f(h));
        }else{
          u16 h = f2bu(v);
          xr[idx] = h;
          if(xrlo) xrlo[idx] = f2bu(v - bu2f(h));
        }
      }
    }
}

// ---------- final: out[b][t][:] = tanh(h(t,b,:) @ W_o + b_o) (fp32) ----------
// hall BLOCK-MAJOR: hall[t][owner(64)][row(32)][16]; owner o holds
//   c<8  -> global col o*8+c ; c>=8 -> o*8 + 512 + (c-8)
__global__ __launch_bounds__(256) void k_fin(const u16* __restrict__ hall,
    const u16* __restrict__ WoTh, const u16* __restrict__ WoTl,
    const float* __restrict__ b_o, float* __restrict__ out){
  int tid = threadIdx.x, l = tid&63, wid = tid>>6;
  int wm = wid>>1, wn = wid&1, lr = l&15, lg = l>>4;
  int mbase = blockIdx.y*64 + wm*32;
  int nbase = blockIdx.x*64 + wn*32;
  size_t arowB[2]; const u16* brh[2]; const u16* brl[2];
  #pragma unroll
  for(int mt=0;mt<2;mt++){
    int m = mbase + mt*16 + lr;                       // m = t*32 + b
    arowB[mt] = (size_t)(m>>5)*FRAME + (size_t)(m&31)*16;
  }
  #pragma unroll
  for(int nt=0;nt<2;nt++){
    brh[nt] = WoTh + (size_t)(nbase + nt*16 + lr)*H_N;
    brl[nt] = WoTl + (size_t)(nbase + nt*16 + lr)*H_N;
  }
  f32x4 zz = {0.f,0.f,0.f,0.f};
  f32x4 acc[2][2] = {{zz,zz},{zz,zz}};
  for(int ks=0;ks<32;ks++){
    int ke = ks*32 + lg*8;
    int abase = ((ks&15)*4 + lg)*512 + ((ks>=16)?8:0);
    #pragma unroll
    for(int mt=0;mt<2;mt++){
      bf16x8 a = ld8(hall + arowB[mt] + abase);
      #pragma unroll
      for(int nt=0;nt<2;nt++){
        acc[mt][nt] = MFMA16(a, ld8(brh[nt]+ke), acc[mt][nt]);
        acc[mt][nt] = MFMA16(a, ld8(brl[nt]+ke), acc[mt][nt]);
      }
    }
  }
  #pragma unroll
  for(int mt=0;mt<2;mt++)
    #pragma unroll
    for(int nt=0;nt<2;nt++){
      int n = nbase + nt*16 + lr;
      float bo = b_o[n];
      #pragma unroll
      for(int i=0;i<4;i++){
        int m = mbase + mt*16 + lg*4 + i;
        int b = m & (B_N-1), t = m >> 5;
        out[((size_t)b*S_N + t)*H_N + n] = tanhf(acc[mt][nt][i] + bo);
      }
    }
}

// ---------- persistent recurrence: 64 blocks x 256 threads -------------------
// Block owns 8 pairs (P0=bid*8). ALL weights staged in LDS once (immune to the
// per-step acquire invalidation). O|P share one 16-col MFMA tile. Poll: every
// wave spins per-lane on all 64 flags (own flag skipped); 3 syncs/step.
__global__ __launch_bounds__(256) void k_recur(
    const u16* __restrict__ xp, const u16* __restrict__ xplo0,
    const u16* __restrict__ xr, const u16* __restrict__ xrlo0, int xlostep,
    const u16* __restrict__ WhTh, const u16* __restrict__ WhTl,
    const u16* __restrict__ WrTh, const u16* __restrict__ wsp,
    const float* __restrict__ b_h, const float* __restrict__ b_r,
    const float* __restrict__ b_s,
    const float* __restrict__ mob_a, const float* __restrict__ mob_b,
    const float* __restrict__ mob_c, const float* __restrict__ mob_d,
    const u16* __restrict__ zhi, u16* __restrict__ lob,
    u16* __restrict__ hall, float* __restrict__ hf, int* __restrict__ arr)
{
  __shared__ u16 wcH[32][512];         // cand tile hi  (32 KB)
  __shared__ u16 wcL[32][512];         // cand tile lo
  __shared__ u16 wrH[32][512];         // r tile hi
  __shared__ u16 wst[32][512];         // Ws padded tile
  __shared__ float Cpart[4][32*36];    // per-wave partials (18 KB)
  __shared__ float mobp[8*25];
  __shared__ float bias[32];
  __shared__ float bsv[3];
  __shared__ float hfL[32][17];        // fp32 master h (cols: 0-7 O, 8-15 P)
  int tid = threadIdx.x, bid = blockIdx.x;
  int P0 = bid*8;
  int l = tid&63, kq = tid>>6;
  int lr = l&15, lg = l>>4;

  // ---- one-time staging ----
  // weights: each wave stages its own 8 K-slots (only it reads them)
  {
    int cl = l & 15, lg2 = l >> 4;
    int gO = P0 + ((cl<8)? cl : 512 + (cl-8));
    #pragma unroll
    for(int i8=0;i8<8;i8++){
      int ks = kq*8 + i8;
      int kk = ks*32 + lg2*8;
      *reinterpret_cast<bf16x8*>(&wcH[ks][l*8]) = ld8(WhTh + (size_t)gO*H_N + kk);
      *reinterpret_cast<bf16x8*>(&wcL[ks][l*8]) = ld8(WhTl + (size_t)gO*H_N + kk);
      *reinterpret_cast<bf16x8*>(&wrH[ks][l*8]) = ld8(WrTh + (size_t)gO*H_N + kk);
      *reinterpret_cast<bf16x8*>(&wst[ks][l*8]) = ld8(wsp + (size_t)ks*512 + l*8);
    }
  }
  if(tid < 192){
    int j = tid/24, c = tid%24, cyc = c>>3, q = c&7;
    const float* arrp = (q<2)? mob_a : (q<4)? mob_b : (q<6)? mob_c : mob_d;
    mobp[j*25 + c] = arrp[cyc*H_N + (q&1)*HH_N + P0 + j];
  } else if(tid < 224){
    int v = tid-192, grp = v>>3, jj = v&7;
    bias[v] = ((grp<2)? b_h : b_r)[P0 + jj + ((grp&1)? HH_N : 0)];
  } else if(tid < 227){
    bsv[tid-224] = b_s[tid-224];
  }
  for(int idx=tid; idx<32*17; idx+=256) (&hfL[0][0])[idx] = 0.f;

  // block-major A addressing: ab = ((kq&1)*32 + i*4 + lg)*512 + (kq>=2 ? 8 : 0)
  int abq = (kq&1)*32*512 + ((kq>=2)?8:0);
  int row0t = lr*16, row1t = (16+lr)*16;
  // elementwise mapping (threads 0..127): (erow, duo)
  int erow = tid>>2, ejj = (tid&3)*2;
  size_t ei0 = (size_t)erow*H_N + P0 + ejj;
  size_t ei1 = ei0 + HH_N;
  bool ew = (tid < 128);

  __syncthreads();

  for(int t=0; t<S_N; t++){
    const u16* hihB = (t==0)? zhi : (hall + (size_t)(t-1)*FRAME);
    const u16* hilB = lob + (size_t)(t&1)*FRAME;

    // prefetch elementwise inputs (constant data, safe pre-poll)
    u32 pxpL=0,pxpH=0,ploL=0,ploH=0,pxrL=0,pxrH=0,prlL=0,prlH=0;
    if(ew){
      const u16* xp_t   = xp + (size_t)t*FRAME;
      const u16* xr_t   = xr + (size_t)t*FRAME;
      const u16* xplo_t = xplo0 + (size_t)t*xlostep;
      const u16* xrlo_t = xrlo0 + (size_t)t*xlostep;
      pxpL = *(const u32*)(xp_t   + ei0);  pxpH = *(const u32*)(xp_t   + ei1);
      ploL = *(const u32*)(xplo_t + ei0);  ploH = *(const u32*)(xplo_t + ei1);
      pxrL = *(const u32*)(xr_t   + ei0);  pxrH = *(const u32*)(xr_t   + ei1);
      prlL = *(const u32*)(xrlo_t + ei0);  prlH = *(const u32*)(xrlo_t + ei1);
    }

    // poll: every wave, per-lane spin on flag l (skip own block's flag)
    if(l != bid){
      while(__hip_atomic_load(&arr[l<<5], __ATOMIC_ACQUIRE, __HIP_MEMORY_SCOPE_AGENT) < t)
        __builtin_amdgcn_s_sleep(1);
    }

    f32x4 zz = {0.f,0.f,0.f,0.f};
    f32x4 c0a=zz,c1a=zz,r0a=zz,r1a=zz,s0a=zz,s1a=zz;
    #pragma unroll
    for(int i=0;i<8;i++){
      int ks = kq*8 + i;
      int ab = abq + (i*4 + lg)*512;
      bf16x8 ah0 = ld8(hihB + ab + row0t);
      bf16x8 ah1 = ld8(hihB + ab + row1t);
      bf16x8 al0 = ld8(hilB + ab + row0t);
      bf16x8 al1 = ld8(hilB + ab + row1t);
      bf16x8 bc  = ld8(&wcH[ks][l*8]);
      bf16x8 bcl = ld8(&wcL[ks][l*8]);
      bf16x8 br_ = ld8(&wrH[ks][l*8]);
      bf16x8 bs_ = ld8(&wst[ks][l*8]);
      c0a = MFMA16(ah0,bc,c0a); c0a = MFMA16(al0,bc,c0a); c0a = MFMA16(ah0,bcl,c0a);
      c1a = MFMA16(ah1,bc,c1a); c1a = MFMA16(al1,bc,c1a); c1a = MFMA16(ah1,bcl,c1a);
      r0a = MFMA16(ah0,br_,r0a); r0a = MFMA16(al0,br_,r0a);
      r1a = MFMA16(ah1,br_,r1a); r1a = MFMA16(al1,br_,r1a);
      s0a = MFMA16(ah0,bs_,s0a); s0a = MFMA16(al0,bs_,s0a);
      s1a = MFMA16(ah1,bs_,s1a); s1a = MFMA16(al1,bs_,s1a);
    }

    // per-wave partials (cols: 0-15 cand, 16-31 r, 32-34 s)
    {
      float* W = Cpart[kq];
      #pragma unroll
      for(int i=0;i<4;i++){
        int r0 = (lg*4+i)*36, r1 = (16+lg*4+i)*36;
        W[r0 + lr]      = c0a[i];  W[r1 + lr]      = c1a[i];
        W[r0 + 16 + lr] = r0a[i];  W[r1 + 16 + lr] = r1a[i];
        if(lr < 3){ W[r0 + 32 + lr] = s0a[i]; W[r1 + 32 + lr] = s1a[i]; }
      }
    }
    __syncthreads();
    for(int e=tid; e<32*36; e+=256)
      Cpart[0][e] = Cpart[0][e] + Cpart[1][e] + Cpart[2][e] + Cpart[3][e];
    __syncthreads();

    // elementwise (threads 0..127): fused softmax + mobius + h update
    if(ew){
      const float* C0 = &Cpart[0][erow*36];
      float l0 = C0[32] + bsv[0];
      float l1 = C0[33] + bsv[1];
      float l2 = C0[34] + bsv[2];
      float mx = fmaxf(l0, fmaxf(l1,l2));
      float e0 = expf(l0-mx), e1 = expf(l1-mx), e2 = expf(l2-mx);
      float sb = (e0 + 0.5f*e1 + 0.25f*e2) / (e0+e1+e2);
      u16 nob[2], npb[2], loO[2], loP[2];
      #pragma unroll
      for(int d=0; d<2; d++){
        int j = ejj + d;
        float xpv0 = bu2f((u16)(pxpL>>(16*d))) + bu2f((u16)(ploL>>(16*d)));
        float xpv1 = bu2f((u16)(pxpH>>(16*d))) + bu2f((u16)(ploH>>(16*d)));
        float xrv0 = bu2f((u16)(pxrL>>(16*d))) + bu2f((u16)(prlL>>(16*d)));
        float xrv1 = bu2f((u16)(pxrH>>(16*d))) + bu2f((u16)(prlH>>(16*d)));
        float zo = tanhf(xpv0 + C0[j]     + bias[j]);
        float zp = tanhf(xpv1 + C0[8+j]   + bias[8+j]);
        float ro = 1.f/(1.f + expf(-(xrv0 + C0[16+j] + bias[16+j])));
        float rp = 1.f/(1.f + expf(-(xrv1 + C0[24+j] + bias[24+j])));
        const float* mp = &mobp[j*25];
        #pragma unroll
        for(int cy=0;cy<3;cy++){
          float are=mp[cy*8+0], aim=mp[cy*8+1], bre=mp[cy*8+2], bim=mp[cy*8+3];
          float cre=mp[cy*8+4], cim=mp[cy*8+5], dre=mp[cy*8+6], dim_=mp[cy*8+7];
          float nre = are*zo - aim*zp + bre;
          float nim = are*zp + aim*zo + bim;
          float de  = cre*zo - cim*zp + dre;
          float di  = cre*zp + cim*zo + dim_;
          float inv = 1.f/(de*de + di*di + EPS_F);
          float nzo = (nre*de + nim*di)*inv;
          float nzp = (nim*de - nre*di)*inv;
          zo = nzo; zp = nzp;
        }
        ro *= sb; rp *= sb;
        float ho = hfL[erow][j], hp2 = hfL[erow][8+j];
        float no  = (1.f-ro)*ho + ro*zo;
        float np2 = (1.f-rp)*hp2 + rp*zp;
        hfL[erow][j] = no; hfL[erow][8+j] = np2;
        nob[d] = f2bu(no);  npb[d] = f2bu(np2);
        loO[d] = f2bu(no  - bu2f(nob[d]));
        loP[d] = f2bu(np2 - bu2f(npb[d]));
      }
      size_t bb = (size_t)bid*512 + (size_t)erow*16 + ejj;
      u16* hallT = hall + (size_t)t*FRAME;
      u16* lonT  = lob + (size_t)((t+1)&1)*FRAME;
      ATOM_ST((u32*)(hallT + bb),     (u32)nob[0] | ((u32)nob[1]<<16));
      ATOM_ST((u32*)(hallT + bb + 8), (u32)npb[0] | ((u32)npb[1]<<16));
      ATOM_ST((u32*)(lonT  + bb),     (u32)loO[0] | ((u32)loO[1]<<16));
      ATOM_ST((u32*)(lonT  + bb + 8), (u32)loP[0] | ((u32)loP[1]<<16));
    }

    // publish: drain stores (syncthreads implies waitcnt), release own flag
    __syncthreads();
    if(tid == 0)
      __hip_atomic_store(&arr[bid<<5], t+1, __ATOMIC_RELEASE, __HIP_MEMORY_SCOPE_AGENT);
  }

  // write fp32 master h out for k_tail
  for(int idx=tid; idx<512; idx+=256){
    int r = idx>>4, c = idx&15;
    int g = (c<8)? (P0+c) : (P0 + HH_N + (c-8));
    hf[(size_t)r*H_N + g] = hfL[r][c];
  }
}

// ---------- tail: of/pf (fp32) from fp32 master h ----------------------------
__global__ __launch_bounds__(256) void k_tail(const float* __restrict__ hf,
                                              float* __restrict__ out){
  int i = blockIdx.x*256 + threadIdx.x;   // 0..32767
  int b = i >> 10, c = i & 1023;
  float v = hf[(size_t)b*H_N + c];
  size_t base = (size_t)B_N*S_N*H_N;
  size_t idx = (c < HH_N) ? base + (size_t)b*HH_N + c
                          : base + (size_t)B_N*HH_N + (size_t)b*HH_N + (c - HH_N);
  out[idx] = v;
}

// ---------- host -------------------------------------------------------------
extern "C" void kernel_launch(void* const* d_in, const int* in_sizes, int n_in,
                              void* d_out, int out_size, void* d_ws, size_t ws_size,
                              hipStream_t stream)
{
  const float* x    = (const float*)d_in[0];
  const float* W_x  = (const float*)d_in[1];
  const float* b_x  = (const float*)d_in[2];
  const float* W_h  = (const float*)d_in[3];
  const float* b_h  = (const float*)d_in[4];
  const float* W_r  = (const float*)d_in[5];
  const float* b_r  = (const float*)d_in[6];
  const float* W_s  = (const float*)d_in[7];
  const float* b_s  = (const float*)d_in[8];
  const float* mob_a= (const float*)d_in[9];
  const float* mob_b= (const float*)d_in[10];
  const float* mob_c= (const float*)d_in[11];
  const float* mob_d= (const float*)d_in[12];
  const float* W_o  = (const float*)d_in[13];
  const float* b_o  = (const float*)d_in[14];
  float* out = (float*)d_out;

  char* ws = (char*)d_ws;
  size_t off = 0;
  auto carve = [&](size_t bytes)->char*{
    char* p = ws + off; off = (off + bytes + 255) & ~(size_t)255; return p;
  };
  int*   arr  = (int*)carve(8192);                          // 64 flags, 128B apart
  float* hf   = (float*)carve((size_t)FRAME*sizeof(float));
  u16*   zhi  = (u16*)carve((size_t)FRAME*sizeof(u16));     // zero h / zero lo frame
  u16*   lob  = (u16*)carve((size_t)2*FRAME*sizeof(u16));
  size_t hdr_bytes = off;                                   // zeroed region
  u16*   WhTh = (u16*)carve((size_t)H_N*H_N*sizeof(u16));
  u16*   WhTl = (u16*)carve((size_t)H_N*H_N*sizeof(u16));
  u16*   WrTh = (u16*)carve((size_t)H_N*H_N*sizeof(u16));
  u16*   wsp  = (u16*)carve((size_t)32*512*sizeof(u16));
  u16*   hall = (u16*)carve((size_t)S_N*FRAME*sizeof(u16));
  u16*   xp   = (u16*)carve((size_t)S_N*FRAME*sizeof(u16));
  u16*   xr   = (u16*)carve((size_t)S_N*FRAME*sizeof(u16));
  size_t base_off = off;
  size_t lo_bytes = (size_t)S_N*FRAME*sizeof(u16);
  bool haslo = (ws_size >= base_off + 2*lo_bytes + 4096);
  u16* xplo = nullptr; u16* xrlo = nullptr;
  if(haslo){
    xplo = (u16*)carve(lo_bytes);
    xrlo = (u16*)carve(lo_bytes);
  }

  const size_t WSZ = (size_t)H_N*H_N;
  u16* WxTh  = hall;             // hall frames 0..127: dead after k_pre
  u16* WxTl  = hall + WSZ;
  u16* WrxTh = hall + 2*WSZ;
  u16* WrxTl = hall + 3*WSZ;
  u16* WoTh  = xp;               // xp dead after recurrence
  u16* WoTl  = xp + WSZ;

  (void)hipMemsetAsync(d_ws, 0, hdr_bytes, stream);

  k_trcvt<<<dim3(32,32),256,0,stream>>>(W_h, WhTh, WhTl);
  k_trcvt<<<dim3(32,32),256,0,stream>>>(W_r + (size_t)H_N*H_N, WrTh, (u16*)nullptr);
  k_trcvt<<<dim3(32,32),256,0,stream>>>(W_x, WxTh, WxTl);
  k_trcvt<<<dim3(32,32),256,0,stream>>>(W_r, WrxTh, WrxTl);
  k_wspack<<<64,256,0,stream>>>(W_s, wsp);
  k_pre<<<dim3(32,256),256,0,stream>>>(x, WxTh, WxTl, WrxTh, WrxTl, b_x,
                                       xp, xplo, xr, xrlo);

  k_recur<<<GBLK,256,0,stream>>>(
      xp, haslo ? xplo : zhi, xr, haslo ? xrlo : zhi, haslo ? FRAME : 0,
      WhTh, WhTl, WrTh, wsp, b_h, b_r, b_s,
      mob_a, mob_b, mob_c, mob_d, zhi, lob, hall, hf, arr);

  k_trcvt<<<dim3(32,32),256,0,stream>>>(W_o, WoTh, WoTl);   // into dead xp
  k_fin<<<dim3(16,256),256,0,stream>>>(hall, WoTh, WoTl, b_o, out);
  k_tail<<<128,256,0,stream>>>(hf, out);
}

// Round 14
// 6408.502 us; speedup vs baseline: 1.2391x; 1.0247x over previous
//
#include <hip/hip_runtime.h>
#include <math.h>

typedef unsigned short u16;
typedef unsigned int u32;
typedef unsigned long long u64;
typedef __attribute__((ext_vector_type(8))) short bf16x8;   // 8 bf16 lanes = 4 VGPR
typedef __attribute__((ext_vector_type(4))) float f32x4;

#define B_N 32
#define S_N 512
#define H_N 1024
#define HH_N 512
#define FRAME (B_N*H_N)        /* 32768 elems */
#define GBLK 32
#define EPS_F 1e-6f

#define MFMA16(a,b,c) __builtin_amdgcn_mfma_f32_16x16x32_bf16((a),(b),(c),0,0,0)
#define ATOM_ST(p,v) __hip_atomic_store((p),(v),__ATOMIC_RELAXED,__HIP_MEMORY_SCOPE_AGENT)

static __device__ __forceinline__ u16 f2bu(float v){      // fp32 -> bf16 bits (RNE)
  union{float f; unsigned u;} x; x.f = v;
  unsigned r = x.u + 0x7FFFu + ((x.u>>16)&1u);
  return (u16)(r>>16);
}
static __device__ __forceinline__ float bu2f(u16 s){
  union{unsigned u; float f;} x; x.u = ((unsigned)s)<<16; return x.f;
}
static __device__ __forceinline__ bf16x8 ld8(const u16* p){
  return *reinterpret_cast<const bf16x8*>(p);
}
// read-through 16B load (2x u64 relaxed agent atomics: sc0/sc1, no cache inv)
static __device__ __forceinline__ bf16x8 ldh16(const u16* p){
  u64 a = __hip_atomic_load((const u64*)p,     __ATOMIC_RELAXED, __HIP_MEMORY_SCOPE_AGENT);
  u64 b = __hip_atomic_load((const u64*)(p+4), __ATOMIC_RELAXED, __HIP_MEMORY_SCOPE_AGENT);
  union{ u64 q[2]; bf16x8 v; } u; u.q[0]=a; u.q[1]=b; return u.v;
}
static __device__ __forceinline__ void cvt8(const float* p, bf16x8& hi, bf16x8& lo){
  #pragma unroll
  for(int j=0;j<8;j++){
    float v = p[j];
    u16 h = f2bu(v);
    hi[j] = (short)h;
    lo[j] = (short)f2bu(v - bu2f(h));
  }
}

// ---------- fp32 1024x1024 transpose+convert: dst[c][k] = bf16(src[k][c]) ----
__global__ __launch_bounds__(256) void k_trcvt(const float* __restrict__ src,
    u16* __restrict__ dh, u16* __restrict__ dl){
  __shared__ float tile[32][33];
  int c0 = blockIdx.x*32, k0 = blockIdx.y*32;
  int tx = threadIdx.x & 31, ty = threadIdx.x >> 5;
  for(int i=ty;i<32;i+=8) tile[i][tx] = src[(size_t)(k0+i)*H_N + c0 + tx];
  __syncthreads();
  for(int i=ty;i<32;i+=8){
    float v = tile[tx][i];
    u16 h = f2bu(v);
    dh[(size_t)(c0+i)*H_N + k0 + tx] = h;
    if(dl) dl[(size_t)(c0+i)*H_N + k0 + tx] = f2bu(v - bu2f(h));
  }
}

// ---------- W_s padded fragment pack (hi only) --------------------------------
__global__ __launch_bounds__(256) void k_wspack(const float* __restrict__ Ws,
                                                u16* __restrict__ wsp){
  int gid = blockIdx.x*256 + threadIdx.x;        // 0..16383
  int j = gid & 7, l = (gid>>3) & 63, ks = gid >> 9;
  int lr = l & 15, lg = l >> 4;
  int k = ks*32 + lg*8 + j;
  wsp[gid] = (lr < 3) ? f2bu(Ws[k*3 + lr]) : (u16)0;
}

// ---------- precompute: xp = tanh(x@W_x+b_x), xr = x@W_r[:D] -----------------
__global__ __launch_bounds__(256) void k_pre(const float* __restrict__ x,
    const u16* __restrict__ WxTh, const u16* __restrict__ WxTl,
    const u16* __restrict__ WrxTh, const u16* __restrict__ WrxTl,
    const float* __restrict__ b_x,
    u16* __restrict__ xp, u16* __restrict__ xplo,
    u16* __restrict__ xr, u16* __restrict__ xrlo){
  int tid = threadIdx.x, l = tid&63, wid = tid>>6;
  int wm = wid>>1, wn = wid&1, lr = l&15, lg = l>>4;
  int mbase = blockIdx.y*64 + wm*32;
  int nblk = blockIdx.x*64;
  bool isX = (nblk < H_N);
  int nbase = nblk + wn*32;
  const u16* WTh = isX? WxTh : WrxTh;
  const u16* WTl = isX? WxTl : WrxTl;
  int nw0 = isX? nbase : (nbase - H_N);
  const float* ar[2]; const u16* brh[2]; const u16* brl[2];
  #pragma unroll
  for(int mt=0;mt<2;mt++){
    int m = mbase + mt*16 + lr;
    ar[mt] = x + ((size_t)(m & (B_N-1))*S_N + (m>>5))*H_N;   // m = t*32 + b
  }
  #pragma unroll
  for(int nt=0;nt<2;nt++){
    brh[nt] = WTh + (size_t)(nw0 + nt*16 + lr)*H_N;
    brl[nt] = WTl + (size_t)(nw0 + nt*16 + lr)*H_N;
  }
  f32x4 zz = {0.f,0.f,0.f,0.f};
  f32x4 acc[2][2] = {{zz,zz},{zz,zz}};
  for(int ks=0;ks<32;ks++){
    int ke = ks*32 + lg*8;
    bf16x8 ah[2], al[2], bh[2], bl[2];
    #pragma unroll
    for(int mt=0;mt<2;mt++) cvt8(ar[mt]+ke, ah[mt], al[mt]);
    #pragma unroll
    for(int nt=0;nt<2;nt++){ bh[nt] = ld8(brh[nt]+ke); bl[nt] = ld8(brl[nt]+ke); }
    #pragma unroll
    for(int mt=0;mt<2;mt++)
      #pragma unroll
      for(int nt=0;nt<2;nt++){
        acc[mt][nt] = MFMA16(ah[mt],bh[nt],acc[mt][nt]);
        acc[mt][nt] = MFMA16(al[mt],bh[nt],acc[mt][nt]);
        acc[mt][nt] = MFMA16(ah[mt],bl[nt],acc[mt][nt]);
      }
  }
  #pragma unroll
  for(int mt=0;mt<2;mt++)
    #pragma unroll
    for(int nt=0;nt<2;nt++){
      int n = nbase + nt*16 + lr;
      #pragma unroll
      for(int i=0;i<4;i++){
        int m = mbase + mt*16 + lg*4 + i;
        size_t idx = (size_t)m*H_N + (isX? n : (n - H_N));
        float v = acc[mt][nt][i];
        if(isX){
          float tv = tanhf(v + b_x[n]);
          u16 h = f2bu(tv);
          xp[idx] = h;
          if(xplo) xplo[idx] = f2bu(tv - bu2f(h));
        }else{
          u16 h = f2bu(v);
          xr[idx] = h;
          if(xrlo) xrlo[idx] = f2bu(v - bu2f(h));
        }
      }
    }
}

// ---------- final: out[b][t][:] = tanh(h(t,b,:) @ W_o + b_o) (fp32) ----------
// hall BLOCK-MAJOR: hall[t][owner(32)][row(32)][c(32)]:
//   c<16 -> global col owner*16+c ; c>=16 -> owner*16 + 512 + (c-16)
__global__ __launch_bounds__(256) void k_fin(const u16* __restrict__ hall,
    const u16* __restrict__ WoTh, const u16* __restrict__ WoTl,
    const float* __restrict__ b_o, float* __restrict__ out){
  int tid = threadIdx.x, l = tid&63, wid = tid>>6;
  int wm = wid>>1, wn = wid&1, lr = l&15, lg = l>>4;
  int mbase = blockIdx.y*64 + wm*32;
  int nbase = blockIdx.x*64 + wn*32;
  size_t arowB[2]; const u16* brh[2]; const u16* brl[2];
  #pragma unroll
  for(int mt=0;mt<2;mt++){
    int m = mbase + mt*16 + lr;                       // m = t*32 + b
    arowB[mt] = (size_t)(m>>5)*FRAME + (size_t)(m&31)*32;
  }
  #pragma unroll
  for(int nt=0;nt<2;nt++){
    brh[nt] = WoTh + (size_t)(nbase + nt*16 + lr)*H_N;
    brl[nt] = WoTl + (size_t)(nbase + nt*16 + lr)*H_N;
  }
  int lgadd = (lg>>1)*1024 + (lg&1)*8;
  f32x4 zz = {0.f,0.f,0.f,0.f};
  f32x4 acc[2][2] = {{zz,zz},{zz,zz}};
  for(int ks=0;ks<32;ks++){
    int ke = ks*32 + lg*8;
    int abase = (2*(ks&15))*1024 + lgadd + ((ks>=16)?16:0);
    #pragma unroll
    for(int mt=0;mt<2;mt++){
      bf16x8 a = ld8(hall + arowB[mt] + abase);
      #pragma unroll
      for(int nt=0;nt<2;nt++){
        acc[mt][nt] = MFMA16(a, ld8(brh[nt]+ke), acc[mt][nt]);
        acc[mt][nt] = MFMA16(a, ld8(brl[nt]+ke), acc[mt][nt]);
      }
    }
  }
  #pragma unroll
  for(int mt=0;mt<2;mt++)
    #pragma unroll
    for(int nt=0;nt<2;nt++){
      int n = nbase + nt*16 + lr;
      float bo = b_o[n];
      #pragma unroll
      for(int i=0;i<4;i++){
        int m = mbase + mt*16 + lg*4 + i;
        int b = m & (B_N-1), t = m >> 5;
        out[((size_t)b*S_N + t)*H_N + n] = tanhf(acc[mt][nt][i] + bo);
      }
    }
}

// ---------- persistent recurrence: 32 blocks x 256 threads -------------------
// Round-10 structure (proven 4400us) with ONE mechanism changed: no acquire
// anywhere in the loop. Flags packed at 4B stride, spun with RELAXED loads
// (read-through at coherence point, no cache invalidation; bounded-spin
// acquire fallback as insurance). h (hall/lob) consumed via RELAXED u64
// atomic loads (read-through). Weights/xp/xr stay hot in L1/L2 across steps.
__global__ __launch_bounds__(256) void k_recur(
    const u16* __restrict__ xp, const u16* __restrict__ xplo0,
    const u16* __restrict__ xr, const u16* __restrict__ xrlo0, int xlostep,
    const u16* __restrict__ WhTh, const u16* __restrict__ WhTl,
    const u16* __restrict__ WrTh, const u16* __restrict__ wsp,
    const float* __restrict__ b_h, const float* __restrict__ b_r,
    const float* __restrict__ b_s,
    const float* __restrict__ mob_a, const float* __restrict__ mob_b,
    const float* __restrict__ mob_c, const float* __restrict__ mob_d,
    const u16* __restrict__ zhi, u16* __restrict__ lob,
    u16* __restrict__ hall, float* __restrict__ hf, int* __restrict__ arr)
{
  __shared__ float Cpart[4][2688];     // per-wave 32 rows x 84-stride (80 used)
  __shared__ float mobp[16*25];
  __shared__ float bias[64];
  __shared__ float bsv[3];
  __shared__ float hfL[32][33];        // fp32 master h, block-private
  int tid = threadIdx.x, bid = blockIdx.x;
  int P0 = bid*16;
  int l = tid&63, kq = tid>>6;
  int lr = l&15, lg = l>>4;

  // one-time staging of per-block params
  for(int idx=tid; idx<384; idx+=256){
    int j = idx/24, c = idx%24, cyc = c>>3, q = c&7;
    const float* arrp = (q<2)? mob_a : (q<4)? mob_b : (q<6)? mob_c : mob_d;
    mobp[j*25 + c] = arrp[cyc*H_N + (q&1)*HH_N + P0 + j];
  }
  if(tid < 64){
    int grp = tid>>4, jj = tid&15;
    bias[tid] = ((grp<2)? b_h : b_r)[P0 + jj + ((grp&1)? HH_N : 0)];
  } else if(tid < 67){
    bsv[tid-64] = b_s[tid-64];
  }
  for(int idx=tid; idx<32*33; idx+=256) (&hfL[0][0])[idx] = 0.f;

  const u16* bhOh = WhTh + (size_t)(P0 + lr)*H_N;
  const u16* bhOl = WhTl + (size_t)(P0 + lr)*H_N;
  const u16* bhPh = WhTh + (size_t)(P0 + HH_N + lr)*H_N;
  const u16* bhPl = WhTl + (size_t)(P0 + HH_N + lr)*H_N;
  const u16* brO  = WrTh + (size_t)(P0 + lr)*H_N;
  const u16* brP  = WrTh + (size_t)(P0 + HH_N + lr)*H_N;
  const u16* wps  = wsp + (size_t)(kq*8)*512 + l*8;
  // block-major A addressing: addr = owner*1024 + row*32 + coff (+16 if k>=512)
  int lgadd = (lg>>1)*1024 + (lg&1)*8 + ((kq>=2)?16:0);
  int row0t = lr*32, row1t = (16+lr)*32;
  // elementwise mapping: thread = (row, pair-duo)
  int erow = tid>>3, ejj = (tid&7)*2;
  size_t ei0 = (size_t)erow*H_N + P0 + ejj;
  size_t ei1 = ei0 + HH_N;

  __syncthreads();

  for(int t=0; t<S_N; t++){
    const u16* hihB = (t==0)? zhi : (hall + (size_t)(t-1)*FRAME);
    const u16* hilB = lob + (size_t)(t&1)*FRAME;
    const u16* xp_t   = xp + (size_t)t*FRAME;
    const u16* xr_t   = xr + (size_t)t*FRAME;
    const u16* xplo_t = xplo0 + (size_t)t*xlostep;
    const u16* xrlo_t = xrlo0 + (size_t)t*xlostep;

    // prefetch elementwise inputs early (cached loads; immutable data)
    u32 pxpL = *(const u32*)(xp_t   + ei0);
    u32 pxpH = *(const u32*)(xp_t   + ei1);
    u32 ploL = *(const u32*)(xplo_t + ei0);
    u32 ploH = *(const u32*)(xplo_t + ei1);
    u32 pxrL = *(const u32*)(xr_t   + ei0);
    u32 pxrH = *(const u32*)(xr_t   + ei1);
    u32 prlL = *(const u32*)(xrlo_t + ei0);
    u32 prlH = *(const u32*)(xrlo_t + ei1);

    f32x4 zz = {0.f,0.f,0.f,0.f};
    f32x4 cO0=zz,cO1=zz,cP0=zz,cP1=zz,rOa=zz,rOb=zz,rPa=zz,rPb=zz,sA=zz,sB=zz;
    #pragma unroll
    for(int i=0;i<8;i++){
      int ke = (kq*8+i)*32 + lg*8;                    // row-major W offset
      int abase = (2*((kq&1)*8+i))*1024 + lgadd;      // block-major h offset
      bf16x8 ah0 = ldh16(hihB + abase + row0t);       // read-through
      bf16x8 ah1 = ldh16(hihB + abase + row1t);
      bf16x8 al0 = ldh16(hilB + abase + row0t);
      bf16x8 al1 = ldh16(hilB + abase + row1t);
      bf16x8 fOh = ld8(bhOh+ke), fOl = ld8(bhOl+ke);  // cached (immutable)
      bf16x8 fPh = ld8(bhPh+ke), fPl = ld8(bhPl+ke);
      bf16x8 frO_ = ld8(brO+ke), frP_ = ld8(brP+ke);
      bf16x8 fs   = ld8(wps + i*512);
      cO0 = MFMA16(ah0,fOh,cO0); cO0 = MFMA16(al0,fOh,cO0); cO0 = MFMA16(ah0,fOl,cO0);
      cO1 = MFMA16(ah1,fOh,cO1); cO1 = MFMA16(al1,fOh,cO1); cO1 = MFMA16(ah1,fOl,cO1);
      cP0 = MFMA16(ah0,fPh,cP0); cP0 = MFMA16(al0,fPh,cP0); cP0 = MFMA16(ah0,fPl,cP0);
      cP1 = MFMA16(ah1,fPh,cP1); cP1 = MFMA16(al1,fPh,cP1); cP1 = MFMA16(ah1,fPl,cP1);
      rOa = MFMA16(ah0,frO_,rOa); rOa = MFMA16(al0,frO_,rOa);
      rOb = MFMA16(ah1,frO_,rOb); rOb = MFMA16(al1,frO_,rOb);
      rPa = MFMA16(ah0,frP_,rPa); rPa = MFMA16(al0,frP_,rPa);
      rPb = MFMA16(ah1,frP_,rPb); rPb = MFMA16(al1,frP_,rPb);
      sA  = MFMA16(ah0,fs, sA);  sA  = MFMA16(al0,fs, sA);
      sB  = MFMA16(ah1,fs, sB);  sB  = MFMA16(al1,fs, sB);
    }

    // 4-way K-reduce: kq0->Cpart0, kq1->Cpart1 write; kq2/kq3 add; merge
    __syncthreads();
    float* D = Cpart[kq&1];
    if(kq < 2){
      #pragma unroll
      for(int i=0;i<4;i++){
        int r0 = (lg*4+i)*84, r1 = (16+lg*4+i)*84;
        D[r0 +      lr] = cO0[i];  D[r1 +      lr] = cO1[i];
        D[r0 + 16 + lr] = cP0[i];  D[r1 + 16 + lr] = cP1[i];
        D[r0 + 32 + lr] = rOa[i];  D[r1 + 32 + lr] = rOb[i];
        D[r0 + 48 + lr] = rPa[i];  D[r1 + 48 + lr] = rPb[i];
        D[r0 + 64 + lr] = sA[i];   D[r1 + 64 + lr] = sB[i];
      }
    }
    __syncthreads();
    if(kq >= 2){
      #pragma unroll
      for(int i=0;i<4;i++){
        int r0 = (lg*4+i)*84, r1 = (16+lg*4+i)*84;
        D[r0 +      lr] += cO0[i];  D[r1 +      lr] += cO1[i];
        D[r0 + 16 + lr] += cP0[i];  D[r1 + 16 + lr] += cP1[i];
        D[r0 + 32 + lr] += rOa[i];  D[r1 + 32 + lr] += rOb[i];
        D[r0 + 48 + lr] += rPa[i];  D[r1 + 48 + lr] += rPb[i];
        D[r0 + 64 + lr] += sA[i];   D[r1 + 64 + lr] += sB[i];
      }
    }
    __syncthreads();
    for(int idx=tid; idx<2560; idx+=256){          // 32 rows x 80 cols
      int r = idx/80, c = idx - r*80;
      Cpart[0][r*84+c] += Cpart[1][r*84+c];
    }
    __syncthreads();

    // elementwise: thread owns (erow, pairs ejj & ejj+1); fused softmax
    {
      const float* C0 = &Cpart[0][erow*84];
      float l0 = C0[64] + bsv[0];
      float l1 = C0[65] + bsv[1];
      float l2 = C0[66] + bsv[2];
      float mx = fmaxf(l0, fmaxf(l1,l2));
      float e0 = expf(l0-mx), e1 = expf(l1-mx), e2 = expf(l2-mx);
      float sb = (e0 + 0.5f*e1 + 0.25f*e2) / (e0+e1+e2);
      u16 nob[2], npb[2], loO[2], loP[2];
      #pragma unroll
      for(int d=0; d<2; d++){
        int j = ejj + d;
        float xpv0 = bu2f((u16)(pxpL>>(16*d))) + bu2f((u16)(ploL>>(16*d)));
        float xpv1 = bu2f((u16)(pxpH>>(16*d))) + bu2f((u16)(ploH>>(16*d)));
        float xrv0 = bu2f((u16)(pxrL>>(16*d))) + bu2f((u16)(prlL>>(16*d)));
        float xrv1 = bu2f((u16)(pxrH>>(16*d))) + bu2f((u16)(prlH>>(16*d)));
        float zo = tanhf(xpv0 + C0[j]      + bias[j]);
        float zp = tanhf(xpv1 + C0[16 + j] + bias[16+j]);
        float ro = 1.f/(1.f + expf(-(xrv0 + C0[32 + j] + bias[32+j])));
        float rp = 1.f/(1.f + expf(-(xrv1 + C0[48 + j] + bias[48+j])));
        const float* mp = &mobp[j*25];
        #pragma unroll
        for(int cy=0;cy<3;cy++){
          float are=mp[cy*8+0], aim=mp[cy*8+1], bre=mp[cy*8+2], bim=mp[cy*8+3];
          float cre=mp[cy*8+4], cim=mp[cy*8+5], dre=mp[cy*8+6], dim_=mp[cy*8+7];
          float nre = are*zo - aim*zp + bre;
          float nim = are*zp + aim*zo + bim;
          float de  = cre*zo - cim*zp + dre;
          float di  = cre*zp + cim*zo + dim_;
          float inv = 1.f/(de*de + di*di + EPS_F);
          float nzo = (nre*de + nim*di)*inv;
          float nzp = (nim*de - nre*di)*inv;
          zo = nzo; zp = nzp;
        }
        ro *= sb; rp *= sb;
        float ho = hfL[erow][j], hp2 = hfL[erow][16+j];
        float no  = (1.f-ro)*ho + ro*zo;
        float np2 = (1.f-rp)*hp2 + rp*zp;
        hfL[erow][j] = no; hfL[erow][16+j] = np2;
        nob[d] = f2bu(no);  npb[d] = f2bu(np2);
        loO[d] = f2bu(no  - bu2f(nob[d]));
        loP[d] = f2bu(np2 - bu2f(npb[d]));
      }
      // block-major contiguous write-through stores (4x u32)
      size_t bb = (size_t)bid*1024 + (size_t)erow*32 + ejj;
      u16* hallT = hall + (size_t)t*FRAME;
      u16* lonT  = lob + (size_t)((t+1)&1)*FRAME;
      ATOM_ST((u32*)(hallT + bb),      (u32)nob[0] | ((u32)nob[1]<<16));
      ATOM_ST((u32*)(hallT + bb + 16), (u32)npb[0] | ((u32)npb[1]<<16));
      ATOM_ST((u32*)(lonT  + bb),      (u32)loO[0] | ((u32)loO[1]<<16));
      ATOM_ST((u32*)(lonT  + bb + 16), (u32)loP[0] | ((u32)loP[1]<<16));
    }

    // publish (release) THEN poll (relaxed, packed flags; acquire fallback)
    __syncthreads();        // all waves' stores drained before the release
    if(tid == 0)
      __hip_atomic_store(&arr[bid], t+1, __ATOMIC_RELEASE, __HIP_MEMORY_SCOPE_AGENT);
    if(tid < GBLK){
      int it = 0;
      while(__hip_atomic_load(&arr[tid], __ATOMIC_RELAXED, __HIP_MEMORY_SCOPE_AGENT) <= t){
        __builtin_amdgcn_s_sleep(1);
        if(++it >= 4096){
          it = 0;
          (void)__hip_atomic_load(&arr[tid], __ATOMIC_ACQUIRE, __HIP_MEMORY_SCOPE_AGENT);
        }
      }
    }
    __syncthreads();
  }

  // write fp32 master h out for k_tail
  for(int idx=tid; idx<1024; idx+=256){
    int r = idx>>5, c = idx&31;
    int g = (c<16)? (P0+c) : (P0 + HH_N + (c-16));
    hf[(size_t)r*H_N + g] = hfL[r][c];
  }
}

// ---------- tail: of/pf (fp32) from fp32 master h ----------------------------
__global__ __launch_bounds__(256) void k_tail(const float* __restrict__ hf,
                                              float* __restrict__ out){
  int i = blockIdx.x*256 + threadIdx.x;   // 0..32767
  int b = i >> 10, c = i & 1023;
  float v = hf[(size_t)b*H_N + c];
  size_t base = (size_t)B_N*S_N*H_N;
  size_t idx = (c < HH_N) ? base + (size_t)b*HH_N + c
                          : base + (size_t)B_N*HH_N + (size_t)b*HH_N + (c - HH_N);
  out[idx] = v;
}

// ---------- host -------------------------------------------------------------
extern "C" void kernel_launch(void* const* d_in, const int* in_sizes, int n_in,
                              void* d_out, int out_size, void* d_ws, size_t ws_size,
                              hipStream_t stream)
{
  const float* x    = (const float*)d_in[0];
  const float* W_x  = (const float*)d_in[1];
  const float* b_x  = (const float*)d_in[2];
  const float* W_h  = (const float*)d_in[3];
  const float* b_h  = (const float*)d_in[4];
  const float* W_r  = (const float*)d_in[5];
  const float* b_r  = (const float*)d_in[6];
  const float* W_s  = (const float*)d_in[7];
  const float* b_s  = (const float*)d_in[8];
  const float* mob_a= (const float*)d_in[9];
  const float* mob_b= (const float*)d_in[10];
  const float* mob_c= (const float*)d_in[11];
  const float* mob_d= (const float*)d_in[12];
  const float* W_o  = (const float*)d_in[13];
  const float* b_o  = (const float*)d_in[14];
  float* out = (float*)d_out;

  char* ws = (char*)d_ws;
  size_t off = 0;
  auto carve = [&](size_t bytes)->char*{
    char* p = ws + off; off = (off + bytes + 255) & ~(size_t)255; return p;
  };
  int*   arr  = (int*)carve(4096);                          // 32 flags, 4B stride
  float* hf   = (float*)carve((size_t)FRAME*sizeof(float));
  u16*   zhi  = (u16*)carve((size_t)FRAME*sizeof(u16));     // zero h / zero lo frame
  u16*   lob  = (u16*)carve((size_t)2*FRAME*sizeof(u16));
  size_t hdr_bytes = off;                                   // zeroed region
  u16*   WhTh = (u16*)carve((size_t)H_N*H_N*sizeof(u16));
  u16*   WhTl = (u16*)carve((size_t)H_N*H_N*sizeof(u16));
  u16*   WrTh = (u16*)carve((size_t)H_N*H_N*sizeof(u16));
  u16*   wsp  = (u16*)carve((size_t)32*512*sizeof(u16));
  u16*   hall = (u16*)carve((size_t)S_N*FRAME*sizeof(u16));
  u16*   xp   = (u16*)carve((size_t)S_N*FRAME*sizeof(u16));
  u16*   xr   = (u16*)carve((size_t)S_N*FRAME*sizeof(u16));
  size_t base_off = off;
  size_t lo_bytes = (size_t)S_N*FRAME*sizeof(u16);
  bool haslo = (ws_size >= base_off + 2*lo_bytes + 4096);
  u16* xplo = nullptr; u16* xrlo = nullptr;
  if(haslo){
    xplo = (u16*)carve(lo_bytes);
    xrlo = (u16*)carve(lo_bytes);
  }

  const size_t WSZ = (size_t)H_N*H_N;
  u16* WxTh  = hall;             // hall frames 0..127: dead after k_pre
  u16* WxTl  = hall + WSZ;
  u16* WrxTh = hall + 2*WSZ;
  u16* WrxTl = hall + 3*WSZ;
  u16* WoTh  = xp;               // xp dead after recurrence
  u16* WoTl  = xp + WSZ;

  (void)hipMemsetAsync(d_ws, 0, hdr_bytes, stream);

  k_trcvt<<<dim3(32,32),256,0,stream>>>(W_h, WhTh, WhTl);
  k_trcvt<<<dim3(32,32),256,0,stream>>>(W_r + (size_t)H_N*H_N, WrTh, (u16*)nullptr);
  k_trcvt<<<dim3(32,32),256,0,stream>>>(W_x, WxTh, WxTl);
  k_trcvt<<<dim3(32,32),256,0,stream>>>(W_r, WrxTh, WrxTl);
  k_wspack<<<64,256,0,stream>>>(W_s, wsp);
  k_pre<<<dim3(32,256),256,0,stream>>>(x, WxTh, WxTl, WrxTh, WrxTl, b_x,
                                       xp, xplo, xr, xrlo);

  k_recur<<<GBLK,256,0,stream>>>(
      xp, haslo ? xplo : zhi, xr, haslo ? xrlo : zhi, haslo ? FRAME : 0,
      WhTh, WhTl, WrTh, wsp, b_h, b_r, b_s,
      mob_a, mob_b, mob_c, mob_d, zhi, lob, hall, hf, arr);

  k_trcvt<<<dim3(32,32),256,0,stream>>>(W_o, WoTh, WoTl);   // into dead xp
  k_fin<<<dim3(16,256),256,0,stream>>>(hall, WoTh, WoTl, b_o, out);
  k_tail<<<128,256,0,stream>>>(hf, out);
}

// Round 15
// 5046.891 us; speedup vs baseline: 1.5734x; 1.2698x over previous
//
#include <hip/hip_runtime.h>
#include <math.h>

typedef unsigned short u16;
typedef unsigned int u32;
typedef __attribute__((ext_vector_type(8))) short bf16x8;   // 8 bf16 lanes = 4 VGPR
typedef __attribute__((ext_vector_type(4))) float f32x4;

#define B_N 32
#define S_N 512
#define H_N 1024
#define HH_N 512
#define FRAME (B_N*H_N)        /* 32768 elems */
#define NCG 64
#define NRG 2
#define GBLK (NCG*NRG)
#define RGSZ 16384             /* elems per rg region in a frame */
#define EPS_F 1e-6f

#define MFMA16(a,b,c) __builtin_amdgcn_mfma_f32_16x16x32_bf16((a),(b),(c),0,0,0)
#define ATOM_ST(p,v) __hip_atomic_store((p),(v),__ATOMIC_RELAXED,__HIP_MEMORY_SCOPE_AGENT)

static __device__ __forceinline__ u16 f2bu(float v){      // fp32 -> bf16 bits (RNE)
  union{float f; unsigned u;} x; x.f = v;
  unsigned r = x.u + 0x7FFFu + ((x.u>>16)&1u);
  return (u16)(r>>16);
}
static __device__ __forceinline__ float bu2f(u16 s){
  union{unsigned u; float f;} x; x.u = ((unsigned)s)<<16; return x.f;
}
static __device__ __forceinline__ bf16x8 ld8(const u16* p){
  return *reinterpret_cast<const bf16x8*>(p);
}
static __device__ __forceinline__ void cvt8(const float* p, bf16x8& hi, bf16x8& lo){
  #pragma unroll
  for(int j=0;j<8;j++){
    float v = p[j];
    u16 h = f2bu(v);
    hi[j] = (short)h;
    lo[j] = (short)f2bu(v - bu2f(h));
  }
}

// ---------- fp32 1024x1024 transpose+convert: dst[c][k] = bf16(src[k][c]) ----
__global__ __launch_bounds__(256) void k_trcvt(const float* __restrict__ src,
    u16* __restrict__ dh, u16* __restrict__ dl){
  __shared__ float tile[32][33];
  int c0 = blockIdx.x*32, k0 = blockIdx.y*32;
  int tx = threadIdx.x & 31, ty = threadIdx.x >> 5;
  for(int i=ty;i<32;i+=8) tile[i][tx] = src[(size_t)(k0+i)*H_N + c0 + tx];
  __syncthreads();
  for(int i=ty;i<32;i+=8){
    float v = tile[tx][i];
    u16 h = f2bu(v);
    dh[(size_t)(c0+i)*H_N + k0 + tx] = h;
    if(dl) dl[(size_t)(c0+i)*H_N + k0 + tx] = f2bu(v - bu2f(h));
  }
}

// ---------- W_s padded fragment pack (hi only) --------------------------------
__global__ __launch_bounds__(256) void k_wspack(const float* __restrict__ Ws,
                                                u16* __restrict__ wsp){
  int gid = blockIdx.x*256 + threadIdx.x;        // 0..16383
  int j = gid & 7, l = (gid>>3) & 63, ks = gid >> 9;
  int lr = l & 15, lg = l >> 4;
  int k = ks*32 + lg*8 + j;
  wsp[gid] = (lr < 3) ? f2bu(Ws[k*3 + lr]) : (u16)0;
}

// ---------- precompute: xp = tanh(x@W_x+b_x), xr = x@W_r[:D] -----------------
__global__ __launch_bounds__(256) void k_pre(const float* __restrict__ x,
    const u16* __restrict__ WxTh, const u16* __restrict__ WxTl,
    const u16* __restrict__ WrxTh, const u16* __restrict__ WrxTl,
    const float* __restrict__ b_x,
    u16* __restrict__ xp, u16* __restrict__ xplo,
    u16* __restrict__ xr, u16* __restrict__ xrlo){
  int tid = threadIdx.x, l = tid&63, wid = tid>>6;
  int wm = wid>>1, wn = wid&1, lr = l&15, lg = l>>4;
  int mbase = blockIdx.y*64 + wm*32;
  int nblk = blockIdx.x*64;
  bool isX = (nblk < H_N);
  int nbase = nblk + wn*32;
  const u16* WTh = isX? WxTh : WrxTh;
  const u16* WTl = isX? WxTl : WrxTl;
  int nw0 = isX? nbase : (nbase - H_N);
  const float* ar[2]; const u16* brh[2]; const u16* brl[2];
  #pragma unroll
  for(int mt=0;mt<2;mt++){
    int m = mbase + mt*16 + lr;
    ar[mt] = x + ((size_t)(m & (B_N-1))*S_N + (m>>5))*H_N;   // m = t*32 + b
  }
  #pragma unroll
  for(int nt=0;nt<2;nt++){
    brh[nt] = WTh + (size_t)(nw0 + nt*16 + lr)*H_N;
    brl[nt] = WTl + (size_t)(nw0 + nt*16 + lr)*H_N;
  }
  f32x4 zz = {0.f,0.f,0.f,0.f};
  f32x4 acc[2][2] = {{zz,zz},{zz,zz}};
  for(int ks=0;ks<32;ks++){
    int ke = ks*32 + lg*8;
    bf16x8 ah[2], al[2], bh[2], bl[2];
    #pragma unroll
    for(int mt=0;mt<2;mt++) cvt8(ar[mt]+ke, ah[mt], al[mt]);
    #pragma unroll
    for(int nt=0;nt<2;nt++){ bh[nt] = ld8(brh[nt]+ke); bl[nt] = ld8(brl[nt]+ke); }
    #pragma unroll
    for(int mt=0;mt<2;mt++)
      #pragma unroll
      for(int nt=0;nt<2;nt++){
        acc[mt][nt] = MFMA16(ah[mt],bh[nt],acc[mt][nt]);
        acc[mt][nt] = MFMA16(al[mt],bh[nt],acc[mt][nt]);
        acc[mt][nt] = MFMA16(ah[mt],bl[nt],acc[mt][nt]);
      }
  }
  #pragma unroll
  for(int mt=0;mt<2;mt++)
    #pragma unroll
    for(int nt=0;nt<2;nt++){
      int n = nbase + nt*16 + lr;
      #pragma unroll
      for(int i=0;i<4;i++){
        int m = mbase + mt*16 + lg*4 + i;
        size_t idx = (size_t)m*H_N + (isX? n : (n - H_N));
        float v = acc[mt][nt][i];
        if(isX){
          float tv = tanhf(v + b_x[n]);
          u16 h = f2bu(tv);
          xp[idx] = h;
          if(xplo) xplo[idx] = f2bu(tv - bu2f(h));
        }else{
          u16 h = f2bu(v);
          xr[idx] = h;
          if(xrlo) xrlo[idx] = f2bu(v - bu2f(h));
        }
      }
    }
}

// ---------- final: out[b][t][:] = tanh(h(t,b,:) @ W_o + b_o) (fp32) ----------
// hall layout: [t][rg(2)][owner(64)][row(16)][16];
//   owner o col c: c<8 -> global col o*8+c ; c>=8 -> o*8 + 512 + (c-8)
__global__ __launch_bounds__(256) void k_fin(const u16* __restrict__ hall,
    const u16* __restrict__ WoTh, const u16* __restrict__ WoTl,
    const float* __restrict__ b_o, float* __restrict__ out){
  int tid = threadIdx.x, l = tid&63, wid = tid>>6;
  int wm = wid>>1, wn = wid&1, lr = l&15, lg = l>>4;
  int mbase = blockIdx.y*64 + wm*32;
  int nbase = blockIdx.x*64 + wn*32;
  size_t arowB[2]; const u16* brh[2]; const u16* brl[2];
  #pragma unroll
  for(int mt=0;mt<2;mt++){
    int m = mbase + mt*16 + lr;                       // m = t*32 + b
    int b = m & 31;
    arowB[mt] = (size_t)(m>>5)*FRAME + (size_t)(b>>4)*RGSZ + (size_t)(b&15)*16;
  }
  #pragma unroll
  for(int nt=0;nt<2;nt++){
    brh[nt] = WoTh + (size_t)(nbase + nt*16 + lr)*H_N;
    brl[nt] = WoTl + (size_t)(nbase + nt*16 + lr)*H_N;
  }
  f32x4 zz = {0.f,0.f,0.f,0.f};
  f32x4 acc[2][2] = {{zz,zz},{zz,zz}};
  for(int ks=0;ks<32;ks++){
    int ke = ks*32 + lg*8;
    int abase = (ks<16) ? (ks*4+lg)*256 : ((ks-16)*4+lg)*256 + 8;
    #pragma unroll
    for(int mt=0;mt<2;mt++){
      bf16x8 a = ld8(hall + arowB[mt] + abase);
      #pragma unroll
      for(int nt=0;nt<2;nt++){
        acc[mt][nt] = MFMA16(a, ld8(brh[nt]+ke), acc[mt][nt]);
        acc[mt][nt] = MFMA16(a, ld8(brl[nt]+ke), acc[mt][nt]);
      }
    }
  }
  #pragma unroll
  for(int mt=0;mt<2;mt++)
    #pragma unroll
    for(int nt=0;nt<2;nt++){
      int n = nbase + nt*16 + lr;
      float bo = b_o[n];
      #pragma unroll
      for(int i=0;i<4;i++){
        int m = mbase + mt*16 + lg*4 + i;
        int b = m & (B_N-1), t = m >> 5;
        out[((size_t)b*S_N + t)*H_N + n] = tanhf(acc[mt][nt][i] + bo);
      }
    }
}

// ---------- persistent recurrence: 128 blocks (64 cg x 2 rg) x 256 threads ----
// Row-split removes 3/4 of per-block h traffic: block owns 8 pairs x 16 rows.
// Weights LDS-resident (r12-proven layout). Barrier: two independent 64-flag
// groups (row groups never exchange data). Protocol = r10's proven winner:
// publish (release) -> acquire-spin on 128B-strided flags -> cached h loads.
__global__ __launch_bounds__(256) void k_recur(
    const u16* __restrict__ xp, const u16* __restrict__ xplo0,
    const u16* __restrict__ xr, const u16* __restrict__ xrlo0, int xlostep,
    const u16* __restrict__ WhTh, const u16* __restrict__ WhTl,
    const u16* __restrict__ WrTh, const u16* __restrict__ wsp,
    const float* __restrict__ b_h, const float* __restrict__ b_r,
    const float* __restrict__ b_s,
    const float* __restrict__ mob_a, const float* __restrict__ mob_b,
    const float* __restrict__ mob_c, const float* __restrict__ mob_d,
    const u16* __restrict__ zhi, u16* __restrict__ lob,
    u16* __restrict__ hall, float* __restrict__ hf, int* __restrict__ arr)
{
  __shared__ u16 wcH[32][512];         // cand tile hi  (32 KB)
  __shared__ u16 wcL[32][512];         // cand tile lo
  __shared__ u16 wrH[32][512];         // r tile hi
  __shared__ u16 wst[32][512];         // Ws padded tile
  __shared__ float Cpart[4][16*36];    // per-wave partials (9 KB)
  __shared__ float mobp[8*25];
  __shared__ float bias[32];
  __shared__ float bsv[3];
  __shared__ float hfL[16][17];        // fp32 master h (cols 0-7 O, 8-15 P)
  int tid = threadIdx.x, bid = blockIdx.x;
  int cg = bid & (NCG-1), rg = bid >> 6;
  int P0 = cg*8;
  size_t rgoff = (size_t)rg*RGSZ;
  int l = tid&63, kq = tid>>6;
  int lr = l&15, lg = l>>4;

  // ---- one-time staging: weights (each wave its own 8 K-slots) ----
  {
    int cl = l & 15, lg2 = l >> 4;
    int gO = P0 + ((cl<8)? cl : 512 + (cl-8));
    #pragma unroll
    for(int i8=0;i8<8;i8++){
      int ks = kq*8 + i8;
      int kk = ks*32 + lg2*8;
      *reinterpret_cast<bf16x8*>(&wcH[ks][l*8]) = ld8(WhTh + (size_t)gO*H_N + kk);
      *reinterpret_cast<bf16x8*>(&wcL[ks][l*8]) = ld8(WhTl + (size_t)gO*H_N + kk);
      *reinterpret_cast<bf16x8*>(&wrH[ks][l*8]) = ld8(WrTh + (size_t)gO*H_N + kk);
      *reinterpret_cast<bf16x8*>(&wst[ks][l*8]) = ld8(wsp + (size_t)ks*512 + l*8);
    }
  }
  if(tid < 192){
    int j = tid/24, c = tid%24, cyc = c>>3, q = c&7;
    const float* arrp = (q<2)? mob_a : (q<4)? mob_b : (q<6)? mob_c : mob_d;
    mobp[j*25 + c] = arrp[cyc*H_N + (q&1)*HH_N + P0 + j];
  } else if(tid < 224){
    int v = tid-192, grp = v>>3, jj = v&7;
    bias[v] = ((grp<2)? b_h : b_r)[P0 + jj + ((grp&1)? HH_N : 0)];
  } else if(tid < 227){
    bsv[tid-224] = b_s[tid-224];
  }
  for(int idx=tid; idx<16*17; idx+=256) (&hfL[0][0])[idx] = 0.f;

  // A addressing: addr = rg-frame + owner*256 + Poff + lr*16
  int abq = (kq&1)*32*256 + ((kq>=2)?8:0);
  int rowt = lr*16;
  // elementwise mapping (threads 0..63): (erow, duo of pairs)
  bool ew = (tid < 64);
  int erow = tid>>2, ejj = (tid&3)*2;
  int grow = rg*16 + erow;
  size_t ei0 = (size_t)grow*H_N + P0 + ejj;
  size_t ei1 = ei0 + HH_N;

  __syncthreads();

  for(int t=0; t<S_N; t++){
    const u16* hihB = ((t==0)? zhi : (hall + (size_t)(t-1)*FRAME)) + rgoff;
    const u16* hilB = lob + (size_t)(t&1)*FRAME + rgoff;

    // prefetch elementwise inputs (immutable; cached)
    u32 pxpL=0,pxpH=0,ploL=0,ploH=0,pxrL=0,pxrH=0,prlL=0,prlH=0;
    if(ew){
      const u16* xp_t   = xp + (size_t)t*FRAME;
      const u16* xr_t   = xr + (size_t)t*FRAME;
      const u16* xplo_t = xplo0 + (size_t)t*xlostep;
      const u16* xrlo_t = xrlo0 + (size_t)t*xlostep;
      pxpL = *(const u32*)(xp_t   + ei0);  pxpH = *(const u32*)(xp_t   + ei1);
      ploL = *(const u32*)(xplo_t + ei0);  ploH = *(const u32*)(xplo_t + ei1);
      pxrL = *(const u32*)(xr_t   + ei0);  pxrH = *(const u32*)(xr_t   + ei1);
      prlL = *(const u32*)(xrlo_t + ei0);  prlH = *(const u32*)(xrlo_t + ei1);
    }

    f32x4 zz = {0.f,0.f,0.f,0.f};
    f32x4 c0a=zz, r0a=zz, s0a=zz;
    #pragma unroll
    for(int i=0;i<8;i++){
      int ks = kq*8 + i;
      int ab = abq + (i*4 + lg)*256;
      bf16x8 ah0 = ld8(hihB + ab + rowt);     // cached (post-acquire fresh)
      bf16x8 al0 = ld8(hilB + ab + rowt);
      bf16x8 bc  = ld8(&wcH[ks][l*8]);
      bf16x8 bcl = ld8(&wcL[ks][l*8]);
      bf16x8 br_ = ld8(&wrH[ks][l*8]);
      bf16x8 bs_ = ld8(&wst[ks][l*8]);
      c0a = MFMA16(ah0,bc,c0a); c0a = MFMA16(al0,bc,c0a); c0a = MFMA16(ah0,bcl,c0a);
      r0a = MFMA16(ah0,br_,r0a); r0a = MFMA16(al0,br_,r0a);
      s0a = MFMA16(ah0,bs_,s0a); s0a = MFMA16(al0,bs_,s0a);
    }

    // per-wave partials (cols 0-15 cand, 16-31 r, 32-34 s)
    {
      float* W = Cpart[kq];
      #pragma unroll
      for(int i=0;i<4;i++){
        int r0 = (lg*4+i)*36;
        W[r0 + lr]      = c0a[i];
        W[r0 + 16 + lr] = r0a[i];
        if(lr < 3) W[r0 + 32 + lr] = s0a[i];
      }
    }
    __syncthreads();
    for(int e=tid; e<16*36; e+=256)
      Cpart[0][e] = Cpart[0][e] + Cpart[1][e] + Cpart[2][e] + Cpart[3][e];
    __syncthreads();

    // elementwise (threads 0..63): fused softmax + mobius + h update
    if(ew){
      const float* C0 = &Cpart[0][erow*36];
      float l0 = C0[32] + bsv[0];
      float l1 = C0[33] + bsv[1];
      float l2 = C0[34] + bsv[2];
      float mx = fmaxf(l0, fmaxf(l1,l2));
      float e0 = expf(l0-mx), e1 = expf(l1-mx), e2 = expf(l2-mx);
      float sb = (e0 + 0.5f*e1 + 0.25f*e2) / (e0+e1+e2);
      u16 nob[2], npb[2], loO[2], loP[2];
      #pragma unroll
      for(int d=0; d<2; d++){
        int j = ejj + d;
        float xpv0 = bu2f((u16)(pxpL>>(16*d))) + bu2f((u16)(ploL>>(16*d)));
        float xpv1 = bu2f((u16)(pxpH>>(16*d))) + bu2f((u16)(ploH>>(16*d)));
        float xrv0 = bu2f((u16)(pxrL>>(16*d))) + bu2f((u16)(prlL>>(16*d)));
        float xrv1 = bu2f((u16)(pxrH>>(16*d))) + bu2f((u16)(prlH>>(16*d)));
        float zo = tanhf(xpv0 + C0[j]     + bias[j]);
        float zp = tanhf(xpv1 + C0[8+j]   + bias[8+j]);
        float ro = 1.f/(1.f + expf(-(xrv0 + C0[16+j] + bias[16+j])));
        float rp = 1.f/(1.f + expf(-(xrv1 + C0[24+j] + bias[24+j])));
        const float* mp = &mobp[j*25];
        #pragma unroll
        for(int cy=0;cy<3;cy++){
          float are=mp[cy*8+0], aim=mp[cy*8+1], bre=mp[cy*8+2], bim=mp[cy*8+3];
          float cre=mp[cy*8+4], cim=mp[cy*8+5], dre=mp[cy*8+6], dim_=mp[cy*8+7];
          float nre = are*zo - aim*zp + bre;
          float nim = are*zp + aim*zo + bim;
          float de  = cre*zo - cim*zp + dre;
          float di  = cre*zp + cim*zo + dim_;
          float inv = 1.f/(de*de + di*di + EPS_F);
          float nzo = (nre*de + nim*di)*inv;
          float nzp = (nim*de - nre*di)*inv;
          zo = nzo; zp = nzp;
        }
        ro *= sb; rp *= sb;
        float ho = hfL[erow][j], hp2 = hfL[erow][8+j];
        float no  = (1.f-ro)*ho + ro*zo;
        float np2 = (1.f-rp)*hp2 + rp*zp;
        hfL[erow][j] = no; hfL[erow][8+j] = np2;
        nob[d] = f2bu(no);  npb[d] = f2bu(np2);
        loO[d] = f2bu(no  - bu2f(nob[d]));
        loP[d] = f2bu(np2 - bu2f(npb[d]));
      }
      // block-major contiguous write-through stores (4x u32)
      size_t bb = rgoff + (size_t)cg*256 + (size_t)erow*16 + ejj;
      u16* hallT = hall + (size_t)t*FRAME;
      u16* lonT  = lob + (size_t)((t+1)&1)*FRAME;
      ATOM_ST((u32*)(hallT + bb),     (u32)nob[0] | ((u32)nob[1]<<16));
      ATOM_ST((u32*)(hallT + bb + 8), (u32)npb[0] | ((u32)npb[1]<<16));
      ATOM_ST((u32*)(lonT  + bb),     (u32)loO[0] | ((u32)loO[1]<<16));
      ATOM_ST((u32*)(lonT  + bb + 8), (u32)loP[0] | ((u32)loP[1]<<16));
    }

    // publish (release) THEN acquire-spin on own rg's 64 flags (r10 protocol)
    __syncthreads();        // all waves' stores drained before the release
    if(tid == 0)
      __hip_atomic_store(&arr[bid<<5], t+1, __ATOMIC_RELEASE, __HIP_MEMORY_SCOPE_AGENT);
    if(tid < NCG){
      int fi = (rg*NCG + tid) << 5;
      while(__hip_atomic_load(&arr[fi], __ATOMIC_ACQUIRE, __HIP_MEMORY_SCOPE_AGENT) <= t)
        __builtin_amdgcn_s_sleep(1);
    }
    __syncthreads();
  }

  // write fp32 master h out for k_tail
  for(int idx=tid; idx<256; idx+=256){
    int r = idx>>4, c = idx&15;
    int g = (c<8)? (P0+c) : (P0 + HH_N + (c-8));
    hf[(size_t)(rg*16 + r)*H_N + g] = hfL[r][c];
  }
}

// ---------- tail: of/pf (fp32) from fp32 master h ----------------------------
__global__ __launch_bounds__(256) void k_tail(const float* __restrict__ hf,
                                              float* __restrict__ out){
  int i = blockIdx.x*256 + threadIdx.x;   // 0..32767
  int b = i >> 10, c = i & 1023;
  float v = hf[(size_t)b*H_N + c];
  size_t base = (size_t)B_N*S_N*H_N;
  size_t idx = (c < HH_N) ? base + (size_t)b*HH_N + c
                          : base + (size_t)B_N*HH_N + (size_t)b*HH_N + (c - HH_N);
  out[idx] = v;
}

// ---------- host -------------------------------------------------------------
extern "C" void kernel_launch(void* const* d_in, const int* in_sizes, int n_in,
                              void* d_out, int out_size, void* d_ws, size_t ws_size,
                              hipStream_t stream)
{
  const float* x    = (const float*)d_in[0];
  const float* W_x  = (const float*)d_in[1];
  const float* b_x  = (const float*)d_in[2];
  const float* W_h  = (const float*)d_in[3];
  const float* b_h  = (const float*)d_in[4];
  const float* W_r  = (const float*)d_in[5];
  const float* b_r  = (const float*)d_in[6];
  const float* W_s  = (const float*)d_in[7];
  const float* b_s  = (const float*)d_in[8];
  const float* mob_a= (const float*)d_in[9];
  const float* mob_b= (const float*)d_in[10];
  const float* mob_c= (const float*)d_in[11];
  const float* mob_d= (const float*)d_in[12];
  const float* W_o  = (const float*)d_in[13];
  const float* b_o  = (const float*)d_in[14];
  float* out = (float*)d_out;

  char* ws = (char*)d_ws;
  size_t off = 0;
  auto carve = [&](size_t bytes)->char*{
    char* p = ws + off; off = (off + bytes + 255) & ~(size_t)255; return p;
  };
  int*   arr  = (int*)carve(GBLK*128);                      // 128 flags, 128B apart
  float* hf   = (float*)carve((size_t)FRAME*sizeof(float));
  u16*   zhi  = (u16*)carve((size_t)FRAME*sizeof(u16));     // zero h / zero lo frame
  u16*   lob  = (u16*)carve((size_t)2*FRAME*sizeof(u16));
  size_t hdr_bytes = off;                                   // zeroed region
  u16*   WhTh = (u16*)carve((size_t)H_N*H_N*sizeof(u16));
  u16*   WhTl = (u16*)carve((size_t)H_N*H_N*sizeof(u16));
  u16*   WrTh = (u16*)carve((size_t)H_N*H_N*sizeof(u16));
  u16*   wsp  = (u16*)carve((size_t)32*512*sizeof(u16));
  u16*   hall = (u16*)carve((size_t)S_N*FRAME*sizeof(u16));
  u16*   xp   = (u16*)carve((size_t)S_N*FRAME*sizeof(u16));
  u16*   xr   = (u16*)carve((size_t)S_N*FRAME*sizeof(u16));
  size_t base_off = off;
  size_t lo_bytes = (size_t)S_N*FRAME*sizeof(u16);
  bool haslo = (ws_size >= base_off + 2*lo_bytes + 4096);
  u16* xplo = nullptr; u16* xrlo = nullptr;
  if(haslo){
    xplo = (u16*)carve(lo_bytes);
    xrlo = (u16*)carve(lo_bytes);
  }

  const size_t WSZ = (size_t)H_N*H_N;
  u16* WxTh  = hall;             // hall frames 0..127: dead after k_pre
  u16* WxTl  = hall + WSZ;
  u16* WrxTh = hall + 2*WSZ;
  u16* WrxTl = hall + 3*WSZ;
  u16* WoTh  = xp;               // xp dead after recurrence
  u16* WoTl  = xp + WSZ;

  (void)hipMemsetAsync(d_ws, 0, hdr_bytes, stream);

  k_trcvt<<<dim3(32,32),256,0,stream>>>(W_h, WhTh, WhTl);
  k_trcvt<<<dim3(32,32),256,0,stream>>>(W_r + (size_t)H_N*H_N, WrTh, (u16*)nullptr);
  k_trcvt<<<dim3(32,32),256,0,stream>>>(W_x, WxTh, WxTl);
  k_trcvt<<<dim3(32,32),256,0,stream>>>(W_r, WrxTh, WrxTl);
  k_wspack<<<64,256,0,stream>>>(W_s, wsp);
  k_pre<<<dim3(32,256),256,0,stream>>>(x, WxTh, WxTl, WrxTh, WrxTl, b_x,
                                       xp, xplo, xr, xrlo);

  k_recur<<<GBLK,256,0,stream>>>(
      xp, haslo ? xplo : zhi, xr, haslo ? xrlo : zhi, haslo ? FRAME : 0,
      WhTh, WhTl, WrTh, wsp, b_h, b_r, b_s,
      mob_a, mob_b, mob_c, mob_d, zhi, lob, hall, hf, arr);

  k_trcvt<<<dim3(32,32),256,0,stream>>>(W_o, WoTh, WoTl);   // into dead xp
  k_fin<<<dim3(16,256),256,0,stream>>>(hall, WoTh, WoTl, b_o, out);
  k_tail<<<128,256,0,stream>>>(hf, out);
}